// Round 8
// baseline (61.175 us; speedup 1.0000x reference)
//
#include <hip/hip_runtime.h>
#include <stdint.h>

typedef unsigned long long u64;
typedef unsigned int u32;

#define VOCAB 128000
#define NV4   32000      // VOCAB/4
#define NROWS 256
#define BLK   1024
#define NW    16
#define NB    4096
#define CAPL  4096
#define SEPS  1e-5f
#define LN2X40 27.725887222397812f   /* 40*ln2 */
#define MAIN4 28672                  /* 7 * 4096 full 4x-unrolled iterations */

// ---------- helpers ----------
__device__ __forceinline__ u32 f2key(float f){
  u32 u = __float_as_uint(f);
  return (u & 0x80000000u) ? ~u : (u | 0x80000000u);   // order-preserving
}
__device__ __forceinline__ float key2f(u32 k){
  u32 u = (k & 0x80000000u) ? (k ^ 0x80000000u) : ~k;
  return __uint_as_float(u);
}

// JAX threefry2x32, key (0,42)
__device__ __forceinline__ void tf2x32(u32 x0, u32 x1, u32 &o0, u32 &o1){
  const u32 k0 = 0u, k1 = 42u, k2 = 0u ^ 42u ^ 0x1BD11BDAu;
  x0 += k0; x1 += k1;
#define TFR(r) { x0 += x1; x1 = (x1 << (r)) | (x1 >> (32 - (r))); x1 ^= x0; }
  TFR(13) TFR(15) TFR(26) TFR(6)
  x0 += k1; x1 += k2 + 1u;
  TFR(17) TFR(29) TFR(16) TFR(24)
  x0 += k2; x1 += k0 + 2u;
  TFR(13) TFR(15) TFR(26) TFR(6)
  x0 += k0; x1 += k1 + 3u;
  TFR(17) TFR(29) TFR(16) TFR(24)
  x0 += k1; x1 += k2 + 4u;
  TFR(13) TFR(15) TFR(26) TFR(6)
  x0 += k2; x1 += k0 + 5u;
#undef TFR
  o0 = x0; o1 = x1;
}
__device__ __forceinline__ u32 gumbel_bits(u32 i){
  u32 o0, o1; tf2x32(0u, i, o0, o1);
  return o0 ^ o1;
}
__device__ __forceinline__ float bits2gumbel(u32 b){
  float f = __uint_as_float(0x3F800000u | (b >> 9)) - 1.0f;  // [0,1)
  float u = fmaxf(1e-10f, f + 1e-10f);
  return -logf(-logf(u));
}

// ---------- crossing searches (reduce + wave-0 descent) ----------
__device__ __forceinline__ void cross4096_u32(
    const u32* arr, u32* aux, u32 target, u32* out_idx, u32* out_before, int t)
{
  aux[t] = arr[4*t+0] + arr[4*t+1] + arr[4*t+2] + arr[4*t+3];
  __syncthreads();
  if (t < 64){
    u32 gs = 0u;
    #pragma unroll
    for (int j=0;j<16;j++) gs += aux[t*16+j];
    u32 pref = gs;
    #pragma unroll
    for (int d=1; d<64; d<<=1){ u32 v = __shfl_up(pref, d, 64); if (t >= d) pref += v; }
    u64 bal = __ballot(pref > target);
    int g = bal ? (__ffsll((long long)bal) - 1) : 63;
    u32 pg = __shfl(pref, g, 64);
    u32 gg = __shfl(gs, g, 64);
    if (t == 0){
      u32 c = pg - gg;
      u32 idx = (u32)(g*64 + 63);
      for (int j=0;j<16;j++){
        u32 v = aux[g*16+j];
        if (c + v > target){
          int base = (g*16+j)*4;
          for (int q=0;q<4;q++){
            u32 w = arr[base+q];
            if (c + w > target){ idx = (u32)(base+q); goto doneu; }
            c += w;
          }
        }
        c += v;
      }
      doneu:
      *out_idx = idx; *out_before = c;
    }
  }
}

__device__ __forceinline__ void cross4096_u64(
    const u64* arr, u64* aux, u64 target, u32* out_idx, u64* out_before, int t)
{
  aux[t] = arr[4*t+0] + arr[4*t+1] + arr[4*t+2] + arr[4*t+3];
  __syncthreads();
  if (t < 64){
    u64 gs = 0ull;
    #pragma unroll
    for (int j=0;j<16;j++) gs += aux[t*16+j];
    u64 pref = gs;
    #pragma unroll
    for (int d=1; d<64; d<<=1){
      u64 v = __shfl_up((unsigned long long)pref, d, 64); if (t >= d) pref += v;
    }
    u64 bal = __ballot(pref > target);
    int g = bal ? (__ffsll((long long)bal) - 1) : 63;
    u64 pg = __shfl((unsigned long long)pref, g, 64);
    u64 gg = __shfl((unsigned long long)gs, g, 64);
    if (t == 0){
      u64 c = pg - gg;
      u32 idx = (u32)(g*64 + 63);
      for (int j=0;j<16;j++){
        u64 v = aux[g*16+j];
        if (c + v > target){
          int base = (g*16+j)*4;
          for (int q=0;q<4;q++){
            u64 w = arr[base+q];
            if (c + w > target){ idx = (u32)(base+q); goto donev; }
            c += w;
          }
        }
        c += v;
      }
      donev:
      *out_idx = idx; *out_before = c;
    }
  }
}

// level-1 mass: derives total and target = (1-topp)*total internally
__device__ __forceinline__ void cross4096_mass(
    const u64* arr, u64* aux, float topp_v, u64* out_target,
    u32* out_idx, u64* out_before, int t)
{
  aux[t] = arr[4*t+0] + arr[4*t+1] + arr[4*t+2] + arr[4*t+3];
  __syncthreads();
  if (t < 64){
    u64 gs = 0ull;
    #pragma unroll
    for (int j=0;j<16;j++) gs += aux[t*16+j];
    u64 pref = gs;
    #pragma unroll
    for (int d=1; d<64; d<<=1){
      u64 v = __shfl_up((unsigned long long)pref, d, 64); if (t >= d) pref += v;
    }
    u64 total = __shfl((unsigned long long)pref, 63, 64);
    u64 target = (u64)((double)(1.0f - topp_v) * (double)total);
    u64 bal = __ballot(pref > target);
    int g = bal ? (__ffsll((long long)bal) - 1) : 63;
    u64 pg = __shfl((unsigned long long)pref, g, 64);
    u64 gg = __shfl((unsigned long long)gs, g, 64);
    if (t == 0){
      u64 c = pg - gg;
      u32 idx = (u32)(g*64 + 63);
      for (int j=0;j<16;j++){
        u64 v = aux[g*16+j];
        if (c + v > target){
          int base = (g*16+j)*4;
          for (int q=0;q<4;q++){
            u64 w = arr[base+q];
            if (c + w > target){ idx = (u32)(base+q); goto donem; }
            c += w;
          }
        }
        c += v;
      }
      donem:
      *out_target = target; *out_idx = idx; *out_before = c;
    }
  }
}

__device__ __forceinline__ void cross256_u32(const u32* arr, u32 target, u32* out_idx, int t){
  if (t < 64){
    u32 gs = arr[4*t+0]+arr[4*t+1]+arr[4*t+2]+arr[4*t+3];
    u32 pref = gs;
    #pragma unroll
    for (int d=1; d<64; d<<=1){ u32 v=__shfl_up(pref,d,64); if (t>=d) pref+=v; }
    u64 bal = __ballot(pref > target);
    int g = bal ? (__ffsll((long long)bal)-1) : 63;
    u32 pg=__shfl(pref,g,64), gg=__shfl(gs,g,64);
    if (t==0){
      u32 c = pg-gg; u32 idx=(u32)(g*4+3);
      for (int q=0;q<4;q++){ u32 w=arr[g*4+q]; if (c+w>target){ idx=(u32)(g*4+q); break; } c+=w; }
      *out_idx = idx;
    }
  }
}
__device__ __forceinline__ void cross256_u64(const u64* arr, u64 target, u32* out_idx, int t){
  if (t < 64){
    u64 gs = arr[4*t+0]+arr[4*t+1]+arr[4*t+2]+arr[4*t+3];
    u64 pref = gs;
    #pragma unroll
    for (int d=1; d<64; d<<=1){
      u64 v=__shfl_up((unsigned long long)pref,d,64); if (t>=d) pref+=v;
    }
    u64 bal = __ballot(pref > target);
    int g = bal ? (__ffsll((long long)bal)-1) : 63;
    u64 pg=__shfl((unsigned long long)pref,g,64), gg=__shfl((unsigned long long)gs,g,64);
    if (t==0){
      u64 c = pg-gg; u32 idx=(u32)(g*4+3);
      for (int q=0;q<4;q++){ u64 w=arr[g*4+q]; if (c+w>target){ idx=(u32)(g*4+q); break; } c+=w; }
      *out_idx = idx;
    }
  }
}

__device__ __forceinline__ void msmerge(float &m1, float &S1, float m2, float S2){
  float mm = fmaxf(m1, m2);
  if (mm == -INFINITY){ m1 = mm; S1 = 0.0f; return; }
  S1 = S1*__expf(m1-mm) + S2*__expf(m2-mm);
  m1 = mm;
}

// block argmax (larger value, then smaller idx) -> out[b]
__device__ __forceinline__ void argmax_write(
    float best, u32 bi, float* wrf, u32* wru, int ln, int wv, int b, int* out)
{
  #pragma unroll
  for (int d=32; d>0; d>>=1){
    float c2=__shfl_down(best,d,64); u32 i2=__shfl_down(bi,d,64);
    if (c2>best || (c2==best && i2<bi)){best=c2;bi=i2;}
  }
  if (ln==0){ wrf[wv]=best; wru[wv]=bi; }
  __syncthreads();
  if (wv==0){
    float b1=(ln<NW)?wrf[ln]:-INFINITY; u32 i1=(ln<NW)?wru[ln]:0xFFFFFFFFu;
    #pragma unroll
    for (int d=32; d>0; d>>=1){
      float b2=__shfl_down(b1,d,64); u32 i2=__shfl_down(i1,d,64);
      if (b2>b1 || (b2==b1 && i2<i1)){b1=b2;i1=i2;}
    }
    if (ln==0) out[b]=(int)i1;
  }
}

// ---------- the fused kernel: one block per row, 2 full streams ----------
__global__ __launch_bounds__(BLK) void k_all(
    const float* __restrict__ logits, const float* __restrict__ temp,
    const float* __restrict__ minp, const int* __restrict__ topk,
    const float* __restrict__ topp, int* __restrict__ out)
{
  __shared__ u32 cnt4[4*NB];       // 64KB: 4-way replicated count hist (wave&3)
  __shared__ u64 massI[NB];        // 32KB
  __shared__ u64 list[CAPL];       // 32KB: (key<<32)|idx
  __shared__ u64 aux64[BLK];       // 8KB scratch (u32-punned too)
  __shared__ float wrf1[NW], wrf2[NW];
  __shared__ u32  wru1[NW], wru2[NW];
  __shared__ float sh_m, sh_Z;
  __shared__ u32 sh_lstar, sh_len, sh_idx, sh_bef32, sh_u1, sh_u2, sh_u3;
  __shared__ u64 sh_bef64, sh_tfix;

  u32* aux32 = (u32*)aux64;
  u32* cnt = cnt4;                 // replica 0 = merged hist after P1

  const int b = blockIdx.x;
  const int t = threadIdx.x;
  const int ln = t & 63, wv = t >> 6;
  const float T = temp[b];
  const float* row = logits + (size_t)b * VOCAB;
  const float4* row4 = (const float4*)row;

  // ======== greedy rows: argmax only (1 stream) ========
  if (T < SEPS){
    float M = -INFINITY; u32 Mi = 0xFFFFFFFFu;
#define GRE(Q, IDX) { \
    float l_=(Q); if (l_ > M){ M = l_; Mi = (u32)(IDX); } }
    for (int i=t; i<MAIN4; i+=4096){
      float4 q0=row4[i], q1=row4[i+1024], q2=row4[i+2048], q3=row4[i+3072];
      GRE(q0.x,i*4+0) GRE(q0.y,i*4+1) GRE(q0.z,i*4+2) GRE(q0.w,i*4+3)
      GRE(q1.x,(i+1024)*4+0) GRE(q1.y,(i+1024)*4+1) GRE(q1.z,(i+1024)*4+2) GRE(q1.w,(i+1024)*4+3)
      GRE(q2.x,(i+2048)*4+0) GRE(q2.y,(i+2048)*4+1) GRE(q2.z,(i+2048)*4+2) GRE(q2.w,(i+2048)*4+3)
      GRE(q3.x,(i+3072)*4+0) GRE(q3.y,(i+3072)*4+1) GRE(q3.z,(i+3072)*4+2) GRE(q3.w,(i+3072)*4+3)
    }
    for (int i=MAIN4+t; i<NV4; i+=BLK){
      float4 q=row4[i];
      GRE(q.x,i*4+0) GRE(q.y,i*4+1) GRE(q.z,i*4+2) GRE(q.w,i*4+3)
    }
#undef GRE
    argmax_write(M, Mi, wrf1, wru1, ln, wv, b, out);
    return;
  }

  // ======== P1: replicated count hist + chain-free online (m,Z), 4x unroll ========
  const float invT = 1.0f / T;
  for (int i=t;i<4*NB;i+=BLK) cnt4[i]=0u;
  for (int i=t;i<NB;i+=BLK) massI[i]=0ull;
  if (t==0) sh_len=0u;
  __syncthreads();

  u32* mycnt = cnt4 + (((u32)wv & 3u) << 12);
  float ms0=-INFINITY,S0=0.0f, ms1=-INFINITY,S1=0.0f,
        ms2=-INFINITY,S2=0.0f, ms3=-INFINITY,S3=0.0f;
#define ONLINE(LV, MS, SS) { \
    float l_ = (LV); \
    atomicAdd(&mycnt[f2key(l_)>>20], 1u); \
    float s_ = l_ * invT; \
    float d_ = s_ - MS; \
    float e_ = __expf(-fabsf(d_)); \
    if (d_ > 0.0f){ SS = fmaf(SS, e_, 1.0f); MS = s_; } else { SS += e_; } \
  }
  for (int i=t; i<MAIN4; i+=4096){
    float4 q0=row4[i], q1=row4[i+1024], q2=row4[i+2048], q3=row4[i+3072];
    ONLINE(q0.x,ms0,S0) ONLINE(q0.y,ms1,S1) ONLINE(q0.z,ms2,S2) ONLINE(q0.w,ms3,S3)
    ONLINE(q1.x,ms0,S0) ONLINE(q1.y,ms1,S1) ONLINE(q1.z,ms2,S2) ONLINE(q1.w,ms3,S3)
    ONLINE(q2.x,ms0,S0) ONLINE(q2.y,ms1,S1) ONLINE(q2.z,ms2,S2) ONLINE(q2.w,ms3,S3)
    ONLINE(q3.x,ms0,S0) ONLINE(q3.y,ms1,S1) ONLINE(q3.z,ms2,S2) ONLINE(q3.w,ms3,S3)
  }
  for (int i=MAIN4+t; i<NV4; i+=BLK){
    float4 q=row4[i];
    ONLINE(q.x,ms0,S0) ONLINE(q.y,ms1,S1) ONLINE(q.z,ms2,S2) ONLINE(q.w,ms3,S3)
  }
#undef ONLINE
  msmerge(ms0,S0,ms1,S1); msmerge(ms2,S2,ms3,S3); msmerge(ms0,S0,ms2,S2);
  #pragma unroll
  for (int d=32; d>0; d>>=1){
    float mz = __shfl_down(ms0, d, 64); float Sz = __shfl_down(S0, d, 64);
    msmerge(ms0, S0, mz, Sz);
  }
  if (ln==0){ wrf1[wv]=ms0; wrf2[wv]=S0; }
  __syncthreads();                        // all P1 atomics complete
  // merge the 4 replicas into replica 0 (each entry owned by one thread)
  for (int i=t; i<NB; i+=BLK){
    u32 s = cnt4[i] + cnt4[NB+i] + cnt4[2*NB+i] + cnt4[3*NB+i];
    cnt4[i] = s;
  }
  if (wv==0){
    float m1 = (ln<NW)? wrf1[ln] : -INFINITY;
    float Sx = (ln<NW)? wrf2[ln] : 0.0f;
    #pragma unroll
    for (int d=32; d>0; d>>=1){
      float mz=__shfl_down(m1,d,64); float Sz=__shfl_down(Sx,d,64);
      msmerge(m1, Sx, mz, Sz);
    }
    if (ln==0){ sh_m = m1; sh_Z = Sx; }
  }
  __syncthreads();
  const float m = sh_m, Z = sh_Z;

  // ---- top-k level-1 crossing over all-token counts ----
  int tk = topk[b]; if (tk < 1) tk = 1; if (tk > VOCAB) tk = VOCAB;
  cross4096_u32(cnt, aux32, (u32)(VOCAB - tk), &sh_idx, &sh_bef32, t);
  __syncthreads();
  const u32 b1k = sh_idx;
  const u32 r1  = (u32)(VOCAB - tk + 1) - sh_bef32;

  // ---- min-p raw cutoff l*: wave-parallel monotone search ----
  if (wv==0){
    const float rhs = minp[b] * (1.0f / Z);
    u32 lo = 0u, hi = 0xFF800000u;       // pred(hi)=true; pred(0)=false (NaN key)
    while (hi - lo > 64u){
      u32 step = (hi - lo) >> 6;
      u32 k = lo + (u32)(ln + 1) * step;
      float e = __expf(fmaf(key2f(k), invT, -m));
      u64 bal = __ballot((e / Z) >= rhs);
      if (bal){
        u32 g = (u32)(__ffsll((long long)bal) - 1);
        hi = lo + (g + 1u) * step;
        lo = lo + g * step;
      } else {
        lo += 64u * step;
      }
    }
    u32 k = lo + 1u + (u32)ln;
    bool ok = (k <= hi);
    float e = __expf(fmaf(key2f(k), invT, -m));
    u64 bal = __ballot(ok && ((e / Z) >= rhs));
    if (ln==0) sh_lstar = bal ? (lo + 1u + (u32)(__ffsll((long long)bal) - 1)) : hi;
  }
  __syncthreads();
  const u32 lstar = sh_lstar;
  const u32 bl = lstar >> 20;

  // ---- Kmin (#tokens buckets > bl), pc (#tokens buckets >= b1k) ----
  {
    u32 pa=0u, pc=0u;
    for (int i=t;i<NB;i+=BLK){
      u32 c = cnt[i];
      if ((u32)i > bl)   pa += c;
      if ((u32)i >= b1k) pc += c;
    }
    #pragma unroll
    for (int d=32; d>0; d>>=1){ pa += __shfl_down(pa,d,64); pc += __shfl_down(pc,d,64); }
    if (ln==0){ wru1[wv]=pa; wru2[wv]=pc; }
    __syncthreads();
    if (t==0){
      u32 a=0u, c2=0u;
      for (int w=0; w<NW; w++){ a += wru1[w]; c2 += wru2[w]; }
      sh_u1 = a; sh_u2 = c2;
    }
    __syncthreads();
  }
  const u32 Kmin = sh_u1;
  const bool kcert = (Kmin >= (u32)tk);
  const u32 CLB = kcert ? b1k : bl;      // if !kcert and kval: b1k==bl (proven r5)
  const u32 listlen = kcert ? sh_u2 : (Kmin + cnt[bl]);
  const bool fastOK = (listlen <= (u32)CAPL);
  const float cs = LN2X40 - m;           // (u64)expf(l*invT + cs) = e^(s-m)*2^40

  // ======== P2: filtered mass hist + K + ballot-aggregated compaction ========
  u32 kc = 0u;
#define P2E(LV, IDX) { \
    float l_ = (LV); u32 key_ = f2key(l_); \
    if (key_ >= lstar){ \
      kc++; \
      u64 lm_ = (u64)__expf(fmaf(l_, invT, cs)); \
      if (lm_) atomicAdd(&massI[key_>>20], lm_); \
    } \
    bool cand_ = fastOK && ((key_>>20) >= CLB); \
    u64 bal_ = __ballot(cand_); \
    if (cand_){ \
      u32 lead_ = (u32)__ffsll((long long)bal_) - 1u; \
      u32 base_ = 0u; \
      if ((u32)ln == lead_) base_ = atomicAdd(&sh_len, (u32)__popcll(bal_)); \
      base_ = __shfl(base_, (int)lead_, 64); \
      u32 p_ = base_ + (u32)__popcll(bal_ & ((1ull << ln) - 1ull)); \
      if (p_ < CAPL) list[p_] = ((u64)key_ << 32) | (u64)(u32)(IDX); \
    } \
  }
  for (int i=t; i<MAIN4; i+=4096){
    float4 q0=row4[i], q1=row4[i+1024], q2=row4[i+2048], q3=row4[i+3072];
    P2E(q0.x,i*4+0) P2E(q0.y,i*4+1) P2E(q0.z,i*4+2) P2E(q0.w,i*4+3)
    P2E(q1.x,(i+1024)*4+0) P2E(q1.y,(i+1024)*4+1) P2E(q1.z,(i+1024)*4+2) P2E(q1.w,(i+1024)*4+3)
    P2E(q2.x,(i+2048)*4+0) P2E(q2.y,(i+2048)*4+1) P2E(q2.z,(i+2048)*4+2) P2E(q2.w,(i+2048)*4+3)
    P2E(q3.x,(i+3072)*4+0) P2E(q3.y,(i+3072)*4+1) P2E(q3.z,(i+3072)*4+2) P2E(q3.w,(i+3072)*4+3)
  }
  for (int i=MAIN4+t; i<NV4; i+=BLK){
    float4 q=row4[i];
    P2E(q.x,i*4+0) P2E(q.y,i*4+1) P2E(q.z,i*4+2) P2E(q.w,i*4+3)
  }
#undef P2E
  #pragma unroll
  for (int d=32; d>0; d>>=1) kc += __shfl_down(kc, d, 64);
  if (ln==0) wru1[wv] = kc;
  __syncthreads();                        // P2 atomics complete here
  if (t==0){ u32 K2=0u; for (int w=0;w<NW;w++) K2 += wru1[w]; sh_u3 = K2; }
  __syncthreads();
  const u32 K = sh_u3;
  const bool kval = (K >= (u32)tk);
  const u32 llen = sh_len;

  cross4096_mass(massI, aux64, topp[b], &sh_tfix, &sh_idx, &sh_bef64, t);
  __syncthreads();
  const u32 b1p = sh_idx;
  const u64 t1  = sh_tfix - sh_bef64;
  const bool needK = kval && (b1p <= b1k);
  const bool needP = (!kval) || (b1p >= b1k);

  u32 kkey = 0u, pkey = 0u;

  if (fastOK){
    // ---- k-refine from list ----
    if (needK){
      for (int i=t;i<NB;i+=BLK) cnt[i]=0u;
      __syncthreads();
      for (u32 i=t; i<llen; i+=BLK){
        u32 key = (u32)(list[i]>>32);
        if ((key>>20) == b1k) atomicAdd(&cnt[(key>>8)&0xFFFu], 1u);
      }
      __syncthreads();
      cross4096_u32(cnt, aux32, r1-1u, &sh_idx, &sh_bef32, t);
      __syncthreads();
      u32 b2k = sh_idx, r2 = r1 - sh_bef32;
      u32 prefk = (b1k<<12) | b2k;
      for (int i=t;i<256;i+=BLK) cnt[i]=0u;
      __syncthreads();
      for (u32 i=t; i<llen; i+=BLK){
        u32 key = (u32)(list[i]>>32);
        if ((key>>8) == prefk) atomicAdd(&cnt[key&0xFFu], 1u);
      }
      __syncthreads();
      cross256_u32(cnt, r2-1u, &sh_idx, t);
      __syncthreads();
      kkey = (prefk<<8) | sh_idx;
    }
    // ---- p-refine from list ----
    if (needP){
      for (int i=t;i<NB;i+=BLK) massI[i]=0ull;
      __syncthreads();
      for (u32 i=t; i<llen; i+=BLK){
        u32 key = (u32)(list[i]>>32);
        if ((key>>20) == b1p && key >= lstar){
          u64 lm = (u64)__expf(fmaf(key2f(key), invT, cs));
          if (lm) atomicAdd(&massI[(key>>8)&0xFFFu], lm);
        }
      }
      __syncthreads();
      cross4096_u64(massI, aux64, t1, &sh_idx, &sh_bef64, t);
      __syncthreads();
      u32 b2p = sh_idx; u64 t2 = t1 - sh_bef64;
      u32 prefp = (b1p<<12) | b2p;
      for (int i=t;i<256;i+=BLK) massI[i]=0ull;
      __syncthreads();
      for (u32 i=t; i<llen; i+=BLK){
        u32 key = (u32)(list[i]>>32);
        if ((key>>8) == prefp && key >= lstar){
          u64 lm = (u64)__expf(fmaf(key2f(key), invT, cs));
          if (lm) atomicAdd(&massI[key&0xFFu], lm);
        }
      }
      __syncthreads();
      cross256_u64(massI, t2, &sh_idx, t);
      __syncthreads();
      pkey = (prefp<<8) | sh_idx;
    }
    const u32 thrkey = kkey > pkey ? kkey : pkey;

    // ---- sampling over list (survivors <= ~63) ----
    float best = -INFINITY; u32 bi = 0xFFFFFFFFu;
    for (u32 i=t; i<llen; i+=BLK){
      u64 e = list[i];
      u32 key = (u32)(e>>32);
      if (key >= thrkey){
        u32 idx = (u32)e;
        u32 c = (u32)b * (u32)VOCAB + idx;
        float cand = key2f(key)*invT + bits2gumbel(gumbel_bits(c));
        if (cand > best || (cand == best && idx < bi)){ best = cand; bi = idx; }
      }
    }
    argmax_write(best, bi, wrf1, wru1, ln, wv, b, out);
    return;
  }

  // ======== slow path (list overflow): full-stream refinement + sampling ========
  for (int i=t;i<NB;i+=BLK){ cnt[i]=0u; massI[i]=0ull; }
  __syncthreads();
  for (int i=t; i<NV4; i+=BLK){
    float4 q = row4[i];
    #pragma unroll
    for (int j=0;j<4;j++){
      float l = (&q.x)[j]; u32 key = f2key(l); u32 hb = key>>20;
      if (needK && hb == b1k) atomicAdd(&cnt[(key>>8)&0xFFFu], 1u);
      if (needP && hb == b1p && key >= lstar){
        u64 lm = (u64)__expf(fmaf(l, invT, cs));
        if (lm) atomicAdd(&massI[(key>>8)&0xFFFu], lm);
      }
    }
  }
  __syncthreads();
  u32 b2k = 0u, r2 = 1u, b2p = 0u; u64 t2 = 0ull;
  if (needK){
    cross4096_u32(cnt, aux32, r1-1u, &sh_idx, &sh_bef32, t);
    __syncthreads();
    b2k = sh_idx; r2 = r1 - sh_bef32;
  }
  if (needP){
    cross4096_u64(massI, aux64, t1, &sh_idx, &sh_bef64, t);
    __syncthreads();
    b2p = sh_idx; t2 = t1 - sh_bef64;
  }
  const u32 prefk = (b1k<<12) | b2k;
  const u32 prefp = (b1p<<12) | b2p;
  for (int i=t;i<256;i+=BLK){ cnt[i]=0u; massI[i]=0ull; }
  __syncthreads();
  for (int i=t; i<NV4; i+=BLK){
    float4 q = row4[i];
    #pragma unroll
    for (int j=0;j<4;j++){
      float l = (&q.x)[j]; u32 key = f2key(l);
      if (needK && (key>>8) == prefk) atomicAdd(&cnt[key&0xFFu], 1u);
      if (needP && (key>>8) == prefp && key >= lstar){
        u64 lm = (u64)__expf(fmaf(l, invT, cs));
        if (lm) atomicAdd(&massI[key&0xFFu], lm);
      }
    }
  }
  __syncthreads();
  if (needK){
    cross256_u32(cnt, r2-1u, &sh_idx, t);
    __syncthreads();
    kkey = (prefk<<8) | sh_idx;
  }
  if (needP){
    cross256_u64(massI, t2, &sh_idx, t);
    __syncthreads();
    pkey = (prefp<<8) | sh_idx;
  }
  const float thrf = key2f(kkey > pkey ? kkey : pkey);
  float best = -INFINITY; u32 bi = 0xFFFFFFFFu;
  for (int i=t; i<NV4; i+=BLK){
    float4 q = row4[i];
    #pragma unroll
    for (int j=0;j<4;j++){
      float l = (&q.x)[j];
      if (l >= thrf){
        u32 idx = (u32)(i*4+j);
        u32 c = (u32)b * (u32)VOCAB + idx;
        float cand = l*invT + bits2gumbel(gumbel_bits(c));
        if (cand > best || (cand == best && idx < bi)){ best = cand; bi = idx; }
      }
    }
  }
  argmax_write(best, bi, wrf1, wru1, ln, wv, b, out);
}

extern "C" void kernel_launch(void* const* d_in, const int* in_sizes, int n_in,
                              void* d_out, int out_size, void* d_ws, size_t ws_size,
                              hipStream_t stream)
{
  const float* logits = (const float*)d_in[0];
  const float* temp   = (const float*)d_in[1];
  const float* minp   = (const float*)d_in[2];
  const int*   topk   = (const int*)d_in[3];
  const float* topp   = (const float*)d_in[4];
  int* out = (int*)d_out;

  hipLaunchKernelGGL(k_all, dim3(NROWS), dim3(BLK), 0, stream,
                     logits, temp, minp, topk, topp, out);
}

// Round 9
// 59.401 us; speedup vs baseline: 1.0299x; 1.0299x over previous
//
#include <hip/hip_runtime.h>
#include <hip/hip_cooperative_groups.h>
#include <stdint.h>

namespace cg = cooperative_groups;

typedef unsigned long long u64;
typedef unsigned int u32;

#define VOCAB 128000
#define NV4   32000      // VOCAB/4
#define HV4   16000      // float4s per half-row
#define NROWS 256
#define BLK   1024
#define NW    16
#define NB    4096
#define CAPL  2048       // coop per-row list capacity (exact precheck + slow path)
#define CAPLS 4096       // fallback single-kernel list capacity
#define SEPS  1e-5f
#define LN2X40 27.725887222397812f   /* 40*ln2 */

// ---------- ws layout (bytes) ----------
#define WS_MASSH   0ull                      /* u64[512][4096] = 16 MB  */
#define WS_LIST    16777216ull               /* u64[256][2048] = 4 MB   */
#define WS_CNTH    20971520ull               /* u32[512][4096] = 8 MB   */
#define WS_PARTS   29360128ull               /* f32[512] Z' partials    */
#define WS_PARTK   29362176ull               /* u32[512] max-key        */
#define WS_PARTGV  29364224ull               /* f32[512] greedy max     */
#define WS_PARTGI  29366272ull               /* u32[512] greedy idx     */
#define WS_LL      29368320ull               /* u32[256] list len       */
#define WS_KP      29369344ull               /* u32[256] kept count     */
#define WS_NEED    29370368ull

// ---------- helpers ----------
__device__ __forceinline__ u32 f2key(float f){
  u32 u = __float_as_uint(f);
  return (u & 0x80000000u) ? ~u : (u | 0x80000000u);   // order-preserving
}
__device__ __forceinline__ float key2f(u32 k){
  u32 u = (k & 0x80000000u) ? (k ^ 0x80000000u) : ~k;
  return __uint_as_float(u);
}

// JAX threefry2x32, key (0,42)
__device__ __forceinline__ void tf2x32(u32 x0, u32 x1, u32 &o0, u32 &o1){
  const u32 k0 = 0u, k1 = 42u, k2 = 0u ^ 42u ^ 0x1BD11BDAu;
  x0 += k0; x1 += k1;
#define TFR(r) { x0 += x1; x1 = (x1 << (r)) | (x1 >> (32 - (r))); x1 ^= x0; }
  TFR(13) TFR(15) TFR(26) TFR(6)
  x0 += k1; x1 += k2 + 1u;
  TFR(17) TFR(29) TFR(16) TFR(24)
  x0 += k2; x1 += k0 + 2u;
  TFR(13) TFR(15) TFR(26) TFR(6)
  x0 += k0; x1 += k1 + 3u;
  TFR(17) TFR(29) TFR(16) TFR(24)
  x0 += k1; x1 += k2 + 4u;
  TFR(13) TFR(15) TFR(26) TFR(6)
  x0 += k2; x1 += k0 + 5u;
#undef TFR
  o0 = x0; o1 = x1;
}
__device__ __forceinline__ u32 gumbel_bits(u32 i){
  u32 o0, o1; tf2x32(0u, i, o0, o1);
  return o0 ^ o1;
}
__device__ __forceinline__ float bits2gumbel(u32 b){
  float f = __uint_as_float(0x3F800000u | (b >> 9)) - 1.0f;  // [0,1)
  float u = fmaxf(1e-10f, f + 1e-10f);
  return -logf(-logf(u));
}

// ---------- crossing searches (reduce + wave-0 descent) ----------
__device__ __forceinline__ void cross4096_u32(
    const u32* arr, u32* aux, u32 target, u32* out_idx, u32* out_before, int t)
{
  aux[t] = arr[4*t+0] + arr[4*t+1] + arr[4*t+2] + arr[4*t+3];
  __syncthreads();
  if (t < 64){
    u32 gs = 0u;
    #pragma unroll
    for (int j=0;j<16;j++) gs += aux[t*16+j];
    u32 pref = gs;
    #pragma unroll
    for (int d=1; d<64; d<<=1){ u32 v = __shfl_up(pref, d, 64); if (t >= d) pref += v; }
    u64 bal = __ballot(pref > target);
    int g = bal ? (__ffsll((long long)bal) - 1) : 63;
    u32 pg = __shfl(pref, g, 64);
    u32 gg = __shfl(gs, g, 64);
    if (t == 0){
      u32 c = pg - gg;
      u32 idx = (u32)(g*64 + 63);
      for (int j=0;j<16;j++){
        u32 v = aux[g*16+j];
        if (c + v > target){
          int base = (g*16+j)*4;
          for (int q=0;q<4;q++){
            u32 w = arr[base+q];
            if (c + w > target){ idx = (u32)(base+q); goto doneu; }
            c += w;
          }
        }
        c += v;
      }
      doneu:
      *out_idx = idx; *out_before = c;
    }
  }
}

__device__ __forceinline__ void cross4096_u64(
    const u64* arr, u64* aux, u64 target, u32* out_idx, u64* out_before, int t)
{
  aux[t] = arr[4*t+0] + arr[4*t+1] + arr[4*t+2] + arr[4*t+3];
  __syncthreads();
  if (t < 64){
    u64 gs = 0ull;
    #pragma unroll
    for (int j=0;j<16;j++) gs += aux[t*16+j];
    u64 pref = gs;
    #pragma unroll
    for (int d=1; d<64; d<<=1){
      u64 v = __shfl_up((unsigned long long)pref, d, 64); if (t >= d) pref += v;
    }
    u64 bal = __ballot(pref > target);
    int g = bal ? (__ffsll((long long)bal) - 1) : 63;
    u64 pg = __shfl((unsigned long long)pref, g, 64);
    u64 gg = __shfl((unsigned long long)gs, g, 64);
    if (t == 0){
      u64 c = pg - gg;
      u32 idx = (u32)(g*64 + 63);
      for (int j=0;j<16;j++){
        u64 v = aux[g*16+j];
        if (c + v > target){
          int base = (g*16+j)*4;
          for (int q=0;q<4;q++){
            u64 w = arr[base+q];
            if (c + w > target){ idx = (u32)(base+q); goto donev; }
            c += w;
          }
        }
        c += v;
      }
      donev:
      *out_idx = idx; *out_before = c;
    }
  }
}

// level-1 mass: derives total and target = (1-topp)*total internally
__device__ __forceinline__ void cross4096_mass(
    const u64* arr, u64* aux, float topp_v, u64* out_target,
    u32* out_idx, u64* out_before, int t)
{
  aux[t] = arr[4*t+0] + arr[4*t+1] + arr[4*t+2] + arr[4*t+3];
  __syncthreads();
  if (t < 64){
    u64 gs = 0ull;
    #pragma unroll
    for (int j=0;j<16;j++) gs += aux[t*16+j];
    u64 pref = gs;
    #pragma unroll
    for (int d=1; d<64; d<<=1){
      u64 v = __shfl_up((unsigned long long)pref, d, 64); if (t >= d) pref += v;
    }
    u64 total = __shfl((unsigned long long)pref, 63, 64);
    u64 target = (u64)((double)(1.0f - topp_v) * (double)total);
    u64 bal = __ballot(pref > target);
    int g = bal ? (__ffsll((long long)bal) - 1) : 63;
    u64 pg = __shfl((unsigned long long)pref, g, 64);
    u64 gg = __shfl((unsigned long long)gs, g, 64);
    if (t == 0){
      u64 c = pg - gg;
      u32 idx = (u32)(g*64 + 63);
      for (int j=0;j<16;j++){
        u64 v = aux[g*16+j];
        if (c + v > target){
          int base = (g*16+j)*4;
          for (int q=0;q<4;q++){
            u64 w = arr[base+q];
            if (c + w > target){ idx = (u32)(base+q); goto donem; }
            c += w;
          }
        }
        c += v;
      }
      donem:
      *out_target = target; *out_idx = idx; *out_before = c;
    }
  }
}

__device__ __forceinline__ void cross256_u32(const u32* arr, u32 target, u32* out_idx, int t){
  if (t < 64){
    u32 gs = arr[4*t+0]+arr[4*t+1]+arr[4*t+2]+arr[4*t+3];
    u32 pref = gs;
    #pragma unroll
    for (int d=1; d<64; d<<=1){ u32 v=__shfl_up(pref,d,64); if (t>=d) pref+=v; }
    u64 bal = __ballot(pref > target);
    int g = bal ? (__ffsll((long long)bal)-1) : 63;
    u32 pg=__shfl(pref,g,64), gg=__shfl(gs,g,64);
    if (t==0){
      u32 c = pg-gg; u32 idx=(u32)(g*4+3);
      for (int q=0;q<4;q++){ u32 w=arr[g*4+q]; if (c+w>target){ idx=(u32)(g*4+q); break; } c+=w; }
      *out_idx = idx;
    }
  }
}
__device__ __forceinline__ void cross256_u64(const u64* arr, u64 target, u32* out_idx, int t){
  if (t < 64){
    u64 gs = arr[4*t+0]+arr[4*t+1]+arr[4*t+2]+arr[4*t+3];
    u64 pref = gs;
    #pragma unroll
    for (int d=1; d<64; d<<=1){
      u64 v=__shfl_up((unsigned long long)pref,d,64); if (t>=d) pref+=v;
    }
    u64 bal = __ballot(pref > target);
    int g = bal ? (__ffsll((long long)bal)-1) : 63;
    u64 pg=__shfl((unsigned long long)pref,g,64), gg=__shfl((unsigned long long)gs,g,64);
    if (t==0){
      u64 c = pg-gg; u32 idx=(u32)(g*4+3);
      for (int q=0;q<4;q++){ u64 w=arr[g*4+q]; if (c+w>target){ idx=(u32)(g*4+q); break; } c+=w; }
      *out_idx = idx;
    }
  }
}

__device__ __forceinline__ void msmerge(float &m1, float &S1, float m2, float S2){
  float mm = fmaxf(m1, m2);
  if (mm == -INFINITY){ m1 = mm; S1 = 0.0f; return; }
  S1 = S1*__expf(m1-mm) + S2*__expf(m2-mm);
  m1 = mm;
}

// block argmax (larger value, then smaller idx) -> out[b]
__device__ __forceinline__ void argmax_write(
    float best, u32 bi, float* wrf, u32* wru, int ln, int wv, int b, int* out)
{
  #pragma unroll
  for (int d=32; d>0; d>>=1){
    float c2=__shfl_down(best,d,64); u32 i2=__shfl_down(bi,d,64);
    if (c2>best || (c2==best && i2<bi)){best=c2;bi=i2;}
  }
  if (ln==0){ wrf[wv]=best; wru[wv]=bi; }
  __syncthreads();
  if (wv==0){
    float b1=(ln<NW)?wrf[ln]:-INFINITY; u32 i1=(ln<NW)?wru[ln]:0xFFFFFFFFu;
    #pragma unroll
    for (int d=32; d>0; d>>=1){
      float b2=__shfl_down(b1,d,64); u32 i2=__shfl_down(i1,d,64);
      if (b2>b1 || (b2==b1 && i2<i1)){b1=b2;i1=i2;}
    }
    if (ln==0) out[b]=(int)i1;
  }
}

// =================== cooperative kernel: 2 blocks per row ===================
__global__ __launch_bounds__(BLK, 8) void k_coop(
    const float* __restrict__ logits, const float* __restrict__ temp,
    const float* __restrict__ minp, const int* __restrict__ topk,
    const float* __restrict__ topp, int* __restrict__ out, char* __restrict__ ws)
{
  cg::grid_group grid = cg::this_grid();

  __shared__ u32 cnt[NB];          // 16KB
  __shared__ u64 massI[NB];        // 32KB
  __shared__ u64 list[CAPL];       // 16KB
  __shared__ u64 aux64[BLK];       // 8KB
  __shared__ float wrf1[NW];
  __shared__ u32  wru1[NW], wru2[NW];
  __shared__ u32 sh_idx, sh_bef32, sh_lstar, sh_u1, sh_u2;
  __shared__ u64 sh_bef64, sh_tfix;

  u32* aux32 = (u32*)aux64;
  u64* massH  = (u64*)(ws + WS_MASSH);
  u64* wsList = (u64*)(ws + WS_LIST);
  u32* cntH   = (u32*)(ws + WS_CNTH);
  float* partS  = (float*)(ws + WS_PARTS);
  u32*   partK  = (u32*)(ws + WS_PARTK);
  float* partGV = (float*)(ws + WS_PARTGV);
  u32*   partGI = (u32*)(ws + WS_PARTGI);
  u32*   LL     = (u32*)(ws + WS_LL);
  u32*   KP     = (u32*)(ws + WS_KP);

  const int bid = blockIdx.x;
  const int r = bid >> 1;
  const int h = bid & 1;
  const int t = threadIdx.x;
  const int ln = t & 63, wv = t >> 6;
  const float T = temp[r];
  const bool greedy = (T < SEPS);
  const float invT = greedy ? 1.0f : (1.0f / T);
  const float* row = logits + (size_t)r * VOCAB;
  const float4* row4 = (const float4*)row;
  const int hb4 = h * HV4, he4 = hb4 + HV4;

  // ======================= PHASE A =======================
  if (t == 0 && h == 0){ LL[r] = 0u; KP[r] = 0u; }
  if (greedy){
    float M = -INFINITY; u32 Mi = 0xFFFFFFFFu;
    for (int i = hb4 + t; i < he4; i += BLK){
      float4 q = row4[i];
      #pragma unroll
      for (int j=0;j<4;j++){
        float l = (&q.x)[j]; u32 gi = (u32)(i*4+j);
        if (l > M){ M = l; Mi = gi; }
      }
    }
    #pragma unroll
    for (int d=32; d>0; d>>=1){
      float M2=__shfl_down(M,d,64); u32 I2=__shfl_down(Mi,d,64);
      if (M2>M || (M2==M && I2<Mi)){ M=M2; Mi=I2; }
    }
    if (ln==0){ wrf1[wv]=M; wru1[wv]=Mi; }
    __syncthreads();
    if (t==0){
      float b1=wrf1[0]; u32 i1=wru1[0];
      for (int w=1; w<NW; w++){
        if (wrf1[w]>b1 || (wrf1[w]==b1 && wru1[w]<i1)){ b1=wrf1[w]; i1=wru1[w]; }
      }
      partGV[bid]=b1; partGI[bid]=i1;
    }
  } else {
    for (int i=t;i<NB;i+=BLK) cnt[i]=0u;
    __syncthreads();
    u32 km = 0u;
    float S0=0.0f,S1=0.0f,S2=0.0f,S3=0.0f;
#define PA(LV, SS) { \
    float l_=(LV); u32 k_=f2key(l_); \
    if (k_>km) km=k_; \
    atomicAdd(&cnt[k_>>20], 1u); \
    SS += __expf(l_*invT); }
    for (int i = hb4 + t; i < he4; i += 2*BLK){
      float4 qa = row4[i];
      int i2 = i + BLK; bool h2 = (i2 < he4);
      float4 qb; if (h2) qb = row4[i2];
      PA(qa.x,S0) PA(qa.y,S1) PA(qa.z,S2) PA(qa.w,S3)
      if (h2){ PA(qb.x,S0) PA(qb.y,S1) PA(qb.z,S2) PA(qb.w,S3) }
    }
#undef PA
    float S = (S0+S1)+(S2+S3);
    #pragma unroll
    for (int d=32; d>0; d>>=1){
      S += __shfl_down(S,d,64);
      u32 k2 = __shfl_down(km,d,64); if (k2>km) km=k2;
    }
    if (ln==0){ wrf1[wv]=S; wru1[wv]=km; }
    __syncthreads();                    // cnt atomics + partials done
    // copy local hist to ws
    for (int i=t;i<NB;i+=BLK) cntH[(size_t)bid*NB + i] = cnt[i];
    if (t==0){
      float St=0.0f; u32 kt=0u;
      for (int w=0; w<NW; w++){ St += wrf1[w]; if (wru1[w]>kt) kt=wru1[w]; }
      partS[bid]=St; partK[bid]=kt;
    }
  }
  __threadfence();
  grid.sync();

  // ======================= PHASE B =======================
  float m=0.0f, Z=1.0f, cs=0.0f;
  u32 b1k=0u, r1=1u, lstar=0u, CLB=0u;
  int tk=1; bool kcert=false, fastOK=false;

  if (greedy){
    if (h==0 && t==0){
      float vA=partGV[bid], vB=partGV[bid+1];
      u32 iA=partGI[bid], iB=partGI[bid+1];
      out[r] = (vB>vA || (vB==vA && iB<iA)) ? (int)iB : (int)iA;
    }
  } else {
    // merge partner hist into LDS
    const int pb = bid ^ 1;
    for (int i=t;i<NB;i+=BLK) cnt[i] += cntH[(size_t)pb*NB + i];
    // merged (m, Z)
    {
      u32 kA = partK[bid & ~1], kB = partK[bid | 1];
      float SA = partS[bid & ~1], SB = partS[bid | 1];
      u32 kmax = kA > kB ? kA : kB;
      m = key2f(kmax) * invT;
      Z = (SA + SB) * __expf(-m);
    }
    cs = LN2X40 - m;
    __syncthreads();

    tk = topk[r]; if (tk < 1) tk = 1; if (tk > VOCAB) tk = VOCAB;
    cross4096_u32(cnt, aux32, (u32)(VOCAB - tk), &sh_idx, &sh_bef32, t);
    __syncthreads();
    b1k = sh_idx;
    r1  = (u32)(VOCAB - tk + 1) - sh_bef32;

    // min-p raw cutoff l*: wave-parallel monotone search
    if (wv==0){
      const float rhs = minp[r] * (1.0f / Z);
      u32 lo = 0u, hi = 0xFF800000u;
      while (hi - lo > 64u){
        u32 step = (hi - lo) >> 6;
        u32 k = lo + (u32)(ln + 1) * step;
        float e = __expf(fmaf(key2f(k), invT, -m));
        u64 bal = __ballot((e / Z) >= rhs);
        if (bal){
          u32 g = (u32)(__ffsll((long long)bal) - 1);
          hi = lo + (g + 1u) * step;
          lo = lo + g * step;
        } else {
          lo += 64u * step;
        }
      }
      u32 k = lo + 1u + (u32)ln;
      bool ok = (k <= hi);
      float e = __expf(fmaf(key2f(k), invT, -m));
      u64 bal = __ballot(ok && ((e / Z) >= rhs));
      if (ln==0) sh_lstar = bal ? (lo + 1u + (u32)(__ffsll((long long)bal) - 1)) : hi;
    }
    __syncthreads();
    lstar = sh_lstar;
    const u32 bl = lstar >> 20;

    // Kmin (#tokens buckets > bl), pc (#tokens buckets >= b1k)
    {
      u32 pa=0u, pc=0u;
      for (int i=t;i<NB;i+=BLK){
        u32 c = cnt[i];
        if ((u32)i > bl)   pa += c;
        if ((u32)i >= b1k) pc += c;
      }
      #pragma unroll
      for (int d=32; d>0; d>>=1){ pa += __shfl_down(pa,d,64); pc += __shfl_down(pc,d,64); }
      if (ln==0){ wru1[wv]=pa; wru2[wv]=pc; }
      __syncthreads();
      if (t==0){
        u32 a=0u, c2=0u;
        for (int w=0; w<NW; w++){ a += wru1[w]; c2 += wru2[w]; }
        sh_u1 = a; sh_u2 = c2;
      }
      __syncthreads();
    }
    const u32 Kmin = sh_u1;
    kcert = (Kmin >= (u32)tk);
    CLB = kcert ? b1k : bl;
    const u32 listCnt = kcert ? sh_u2 : (Kmin + cnt[bl]);
    fastOK = (listCnt <= (u32)CAPL);
  }

  // ======================= PHASE C =======================
  if (!greedy){
    for (int i=t;i<NB;i+=BLK) massI[i]=0ull;
    __syncthreads();
    u32 kc = 0u;
#define PC(LV, IDX) { \
    float l_ = (LV); u32 key_ = f2key(l_); \
    if (key_ >= lstar){ \
      kc++; \
      u64 lm_ = (u64)__expf(fmaf(l_, invT, cs)); \
      if (lm_) atomicAdd(&massI[key_>>20], lm_); \
    } \
    bool cand_ = fastOK && ((key_>>20) >= CLB); \
    u64 bal_ = __ballot(cand_); \
    if (cand_){ \
      u32 lead_ = (u32)__ffsll((long long)bal_) - 1u; \
      u32 base_ = 0u; \
      if ((u32)ln == lead_) base_ = atomicAdd(&LL[r], (u32)__popcll(bal_)); \
      base_ = __shfl(base_, (int)lead_, 64); \
      u32 p_ = base_ + (u32)__popcll(bal_ & ((1ull << ln) - 1ull)); \
      if (p_ < CAPL) wsList[(size_t)r*CAPL + p_] = ((u64)key_ << 32) | (u64)(u32)(IDX); \
    } }
    for (int i = hb4 + t; i < he4; i += 2*BLK){
      float4 qa = row4[i];
      int i2 = i + BLK; bool h2 = (i2 < he4);
      float4 qb; if (h2) qb = row4[i2];
      PC(qa.x,i*4+0) PC(qa.y,i*4+1) PC(qa.z,i*4+2) PC(qa.w,i*4+3)
      if (h2){ PC(qb.x,i2*4+0) PC(qb.y,i2*4+1) PC(qb.z,i2*4+2) PC(qb.w,i2*4+3) }
    }
#undef PC
    #pragma unroll
    for (int d=32; d>0; d>>=1) kc += __shfl_down(kc, d, 64);
    if (ln==0) wru1[wv] = kc;
    __syncthreads();                   // mass atomics done
    if (t==0){
      u32 K2=0u; for (int w=0;w<NW;w++) K2 += wru1[w];
      atomicAdd(&KP[r], K2);
    }
    if (h==1){
      for (int i=t;i<NB;i+=BLK) massH[(size_t)bid*NB + i] = massI[i];
    }
  }
  __threadfence();
  grid.sync();

  // ======================= PHASE D (h==0, non-greedy) =======================
  if (greedy || h != 0) return;

  // merge partner mass
  for (int i=t;i<NB;i+=BLK) massI[i] += massH[(size_t)(bid+1)*NB + i];
  __syncthreads();
  const u32 K = KP[r];
  const bool kval = (K >= (u32)tk);
  u32 llen = LL[r]; if (llen > (u32)CAPL) llen = CAPL;

  cross4096_mass(massI, aux64, topp[r], &sh_tfix, &sh_idx, &sh_bef64, t);
  __syncthreads();
  const u32 b1p = sh_idx;
  const u64 t1  = sh_tfix - sh_bef64;
  const bool needK = kval && (b1p <= b1k);
  const bool needP = (!kval) || (b1p >= b1k);

  u32 kkey = 0u, pkey = 0u;

  if (fastOK){
    for (u32 i=t; i<llen; i+=BLK) list[i] = wsList[(size_t)r*CAPL + i];
    __syncthreads();
    if (needK){
      for (int i=t;i<NB;i+=BLK) cnt[i]=0u;
      __syncthreads();
      for (u32 i=t; i<llen; i+=BLK){
        u32 key = (u32)(list[i]>>32);
        if ((key>>20) == b1k) atomicAdd(&cnt[(key>>8)&0xFFFu], 1u);
      }
      __syncthreads();
      cross4096_u32(cnt, aux32, r1-1u, &sh_idx, &sh_bef32, t);
      __syncthreads();
      u32 b2k = sh_idx, r2 = r1 - sh_bef32;
      u32 prefk = (b1k<<12) | b2k;
      for (int i=t;i<256;i+=BLK) cnt[i]=0u;
      __syncthreads();
      for (u32 i=t; i<llen; i+=BLK){
        u32 key = (u32)(list[i]>>32);
        if ((key>>8) == prefk) atomicAdd(&cnt[key&0xFFu], 1u);
      }
      __syncthreads();
      cross256_u32(cnt, r2-1u, &sh_idx, t);
      __syncthreads();
      kkey = (prefk<<8) | sh_idx;
    }
    if (needP){
      for (int i=t;i<NB;i+=BLK) massI[i]=0ull;
      __syncthreads();
      for (u32 i=t; i<llen; i+=BLK){
        u32 key = (u32)(list[i]>>32);
        if ((key>>20) == b1p && key >= lstar){
          u64 lm = (u64)__expf(fmaf(key2f(key), invT, cs));
          if (lm) atomicAdd(&massI[(key>>8)&0xFFFu], lm);
        }
      }
      __syncthreads();
      cross4096_u64(massI, aux64, t1, &sh_idx, &sh_bef64, t);
      __syncthreads();
      u32 b2p = sh_idx; u64 t2 = t1 - sh_bef64;
      u32 prefp = (b1p<<12) | b2p;
      for (int i=t;i<256;i+=BLK) massI[i]=0ull;
      __syncthreads();
      for (u32 i=t; i<llen; i+=BLK){
        u32 key = (u32)(list[i]>>32);
        if ((key>>8) == prefp && key >= lstar){
          u64 lm = (u64)__expf(fmaf(key2f(key), invT, cs));
          if (lm) atomicAdd(&massI[key&0xFFu], lm);
        }
      }
      __syncthreads();
      cross256_u64(massI, t2, &sh_idx, t);
      __syncthreads();
      pkey = (prefp<<8) | sh_idx;
    }
    const u32 thrkey = kkey > pkey ? kkey : pkey;

    float best = -INFINITY; u32 bi = 0xFFFFFFFFu;
    for (u32 i=t; i<llen; i+=BLK){
      u64 e = list[i];
      u32 key = (u32)(e>>32);
      if (key >= thrkey){
        u32 idx = (u32)e;
        u32 c = (u32)r * (u32)VOCAB + idx;
        float cand = key2f(key)*invT + bits2gumbel(gumbel_bits(c));
        if (cand > best || (cand == best && idx < bi)){ best = cand; bi = idx; }
      }
    }
    argmax_write(best, bi, wrf1, wru1, ln, wv, r, out);
    return;
  }

  // ---- slow path: full-row restream refinement + sampling ----
  for (int i=t;i<NB;i+=BLK) cnt[i]=0u;
  { __syncthreads(); }
  for (int i=t;i<NB;i+=BLK) massI[i]=0ull;
  __syncthreads();
  for (int i=t; i<NV4; i+=BLK){
    float4 q = row4[i];
    #pragma unroll
    for (int j=0;j<4;j++){
      float l = (&q.x)[j]; u32 key = f2key(l); u32 hb = key>>20;
      if (needK && hb == b1k) atomicAdd(&cnt[(key>>8)&0xFFFu], 1u);
      if (needP && hb == b1p && key >= lstar){
        u64 lm = (u64)__expf(fmaf(l, invT, cs));
        if (lm) atomicAdd(&massI[(key>>8)&0xFFFu], lm);
      }
    }
  }
  __syncthreads();
  u32 b2k = 0u, r2 = 1u, b2p = 0u; u64 t2 = 0ull;
  if (needK){
    cross4096_u32(cnt, aux32, r1-1u, &sh_idx, &sh_bef32, t);
    __syncthreads();
    b2k = sh_idx; r2 = r1 - sh_bef32;
  }
  if (needP){
    cross4096_u64(massI, aux64, t1, &sh_idx, &sh_bef64, t);
    __syncthreads();
    b2p = sh_idx; t2 = t1 - sh_bef64;
  }
  const u32 prefk = (b1k<<12) | b2k;
  const u32 prefp = (b1p<<12) | b2p;
  for (int i=t;i<256;i+=BLK){ cnt[i]=0u; massI[i]=0ull; }
  __syncthreads();
  for (int i=t; i<NV4; i+=BLK){
    float4 q = row4[i];
    #pragma unroll
    for (int j=0;j<4;j++){
      float l = (&q.x)[j]; u32 key = f2key(l);
      if (needK && (key>>8) == prefk) atomicAdd(&cnt[key&0xFFu], 1u);
      if (needP && (key>>8) == prefp && key >= lstar){
        u64 lm = (u64)__expf(fmaf(l, invT, cs));
        if (lm) atomicAdd(&massI[key&0xFFu], lm);
      }
    }
  }
  __syncthreads();
  if (needK){
    cross256_u32(cnt, r2-1u, &sh_idx, t);
    __syncthreads();
    kkey = (prefk<<8) | sh_idx;
  }
  if (needP){
    cross256_u64(massI, t2, &sh_idx, t);
    __syncthreads();
    pkey = (prefp<<8) | sh_idx;
  }
  const float thrf = key2f(kkey > pkey ? kkey : pkey);
  float best = -INFINITY; u32 bi = 0xFFFFFFFFu;
  for (int i=t; i<NV4; i+=BLK){
    float4 q = row4[i];
    #pragma unroll
    for (int j=0;j<4;j++){
      float l = (&q.x)[j];
      if (l >= thrf){
        u32 idx = (u32)(i*4+j);
        u32 c = (u32)r * (u32)VOCAB + idx;
        float cand = l*invT + bits2gumbel(gumbel_bits(c));
        if (cand > best || (cand == best && idx < bi)){ best = cand; bi = idx; }
      }
    }
  }
  argmax_write(best, bi, wrf1, wru1, ln, wv, r, out);
}

// =================== fallback: r7 single-block kernel (proven 60 µs) ===================
__global__ __launch_bounds__(BLK) void k_single(
    const float* __restrict__ logits, const float* __restrict__ temp,
    const float* __restrict__ minp, const int* __restrict__ topk,
    const float* __restrict__ topp, int* __restrict__ out)
{
  __shared__ u32 cnt[NB];
  __shared__ u64 massI[NB];
  __shared__ u64 list[CAPLS];
  __shared__ u64 aux64[BLK];
  __shared__ float wrf1[NW], wrf2[NW];
  __shared__ u32  wru1[NW], wru2[NW];
  __shared__ float sh_m, sh_Z;
  __shared__ u32 sh_lstar, sh_len, sh_idx, sh_bef32, sh_u1, sh_u2, sh_u3;
  __shared__ u64 sh_bef64, sh_tfix;

  u32* aux32 = (u32*)aux64;

  const int b = blockIdx.x;
  const int t = threadIdx.x;
  const int ln = t & 63, wv = t >> 6;
  const float T = temp[b];
  const float* row = logits + (size_t)b * VOCAB;
  const float4* row4 = (const float4*)row;

  if (T < SEPS){
    float M = -INFINITY; u32 Mi = 0xFFFFFFFFu;
    for (int i=t; i<NV4; i+=BLK){
      float4 q = row4[i];
      #pragma unroll
      for (int j=0;j<4;j++){
        float l = (&q.x)[j]; u32 gi = (u32)(i*4+j);
        if (l > M){ M = l; Mi = gi; }
      }
    }
    argmax_write(M, Mi, wrf1, wru1, ln, wv, b, out);
    return;
  }

  const float invT = 1.0f / T;
  for (int i=t;i<NB;i+=BLK){ cnt[i]=0u; massI[i]=0ull; }
  if (t==0) sh_len=0u;
  __syncthreads();

  float ms0=-INFINITY,S0=0.0f, ms1=-INFINITY,S1=0.0f,
        ms2=-INFINITY,S2=0.0f, ms3=-INFINITY,S3=0.0f;
#define ONLINE(LV, MS, SS) { \
    float l_ = (LV); \
    atomicAdd(&cnt[f2key(l_)>>20], 1u); \
    float s_ = l_ * invT; \
    float d_ = s_ - MS; \
    float e_ = __expf(-fabsf(d_)); \
    if (d_ > 0.0f){ SS = fmaf(SS, e_, 1.0f); MS = s_; } else { SS += e_; } \
  }
  for (int i=t; i<NV4; i+=2*BLK){
    float4 qa = row4[i];
    int i2 = i + BLK; bool h2 = (i2 < NV4);
    float4 qb; if (h2) qb = row4[i2];
    ONLINE(qa.x,ms0,S0) ONLINE(qa.y,ms1,S1) ONLINE(qa.z,ms2,S2) ONLINE(qa.w,ms3,S3)
    if (h2){
      ONLINE(qb.x,ms0,S0) ONLINE(qb.y,ms1,S1) ONLINE(qb.z,ms2,S2) ONLINE(qb.w,ms3,S3)
    }
  }
#undef ONLINE
  msmerge(ms0,S0,ms1,S1); msmerge(ms2,S2,ms3,S3); msmerge(ms0,S0,ms2,S2);
  #pragma unroll
  for (int d=32; d>0; d>>=1){
    float mz = __shfl_down(ms0, d, 64); float Sz = __shfl_down(S0, d, 64);
    msmerge(ms0, S0, mz, Sz);
  }
  if (ln==0){ wrf1[wv]=ms0; wrf2[wv]=S0; }
  __syncthreads();
  if (wv==0){
    float m1 = (ln<NW)? wrf1[ln] : -INFINITY;
    float Sx = (ln<NW)? wrf2[ln] : 0.0f;
    #pragma unroll
    for (int d=32; d>0; d>>=1){
      float mz=__shfl_down(m1,d,64); float Sz=__shfl_down(Sx,d,64);
      msmerge(m1, Sx, mz, Sz);
    }
    if (ln==0){ sh_m = m1; sh_Z = Sx; }
  }
  __syncthreads();
  const float m = sh_m, Z = sh_Z;

  int tk = topk[b]; if (tk < 1) tk = 1; if (tk > VOCAB) tk = VOCAB;
  cross4096_u32(cnt, aux32, (u32)(VOCAB - tk), &sh_idx, &sh_bef32, t);
  __syncthreads();
  const u32 b1k = sh_idx;
  const u32 r1  = (u32)(VOCAB - tk + 1) - sh_bef32;

  if (wv==0){
    const float rhs = minp[b] * (1.0f / Z);
    u32 lo = 0u, hi = 0xFF800000u;
    while (hi - lo > 64u){
      u32 step = (hi - lo) >> 6;
      u32 k = lo + (u32)(ln + 1) * step;
      float e = __expf(fmaf(key2f(k), invT, -m));
      u64 bal = __ballot((e / Z) >= rhs);
      if (bal){
        u32 g = (u32)(__ffsll((long long)bal) - 1);
        hi = lo + (g + 1u) * step;
        lo = lo + g * step;
      } else {
        lo += 64u * step;
      }
    }
    u32 k = lo + 1u + (u32)ln;
    bool ok = (k <= hi);
    float e = __expf(fmaf(key2f(k), invT, -m));
    u64 bal = __ballot(ok && ((e / Z) >= rhs));
    if (ln==0) sh_lstar = bal ? (lo + 1u + (u32)(__ffsll((long long)bal) - 1)) : hi;
  }
  __syncthreads();
  const u32 lstar = sh_lstar;
  const u32 bl = lstar >> 20;

  {
    u32 pa=0u, pc=0u;
    for (int i=t;i<NB;i+=BLK){
      u32 c = cnt[i];
      if ((u32)i > bl)   pa += c;
      if ((u32)i >= b1k) pc += c;
    }
    #pragma unroll
    for (int d=32; d>0; d>>=1){ pa += __shfl_down(pa,d,64); pc += __shfl_down(pc,d,64); }
    if (ln==0){ wru1[wv]=pa; wru2[wv]=pc; }
    __syncthreads();
    if (t==0){
      u32 a=0u, c2=0u;
      for (int w=0; w<NW; w++){ a += wru1[w]; c2 += wru2[w]; }
      sh_u1 = a; sh_u2 = c2;
    }
    __syncthreads();
  }
  const u32 Kmin = sh_u1;
  const bool kcert = (Kmin >= (u32)tk);
  const u32 CLB = kcert ? b1k : bl;
  const u32 listlen = kcert ? sh_u2 : (Kmin + cnt[bl]);
  const bool fastOK = (listlen <= (u32)CAPLS);
  const float cs = LN2X40 - m;

  u32 kc = 0u;
#define P2E(LV, IDX) { \
    float l_ = (LV); u32 key_ = f2key(l_); \
    if (key_ >= lstar){ \
      kc++; \
      u64 lm_ = (u64)__expf(fmaf(l_, invT, cs)); \
      if (lm_) atomicAdd(&massI[key_>>20], lm_); \
    } \
    if (fastOK && (key_>>20) >= CLB){ \
      u32 p_ = atomicAdd(&sh_len, 1u); \
      if (p_ < CAPLS) list[p_] = ((u64)key_ << 32) | (u64)(u32)(IDX); \
    } \
  }
  for (int i=t; i<NV4; i+=2*BLK){
    float4 qa = row4[i];
    int i2 = i + BLK; bool h2 = (i2 < NV4);
    float4 qb; if (h2) qb = row4[i2];
    P2E(qa.x, i*4+0) P2E(qa.y, i*4+1) P2E(qa.z, i*4+2) P2E(qa.w, i*4+3)
    if (h2){
      P2E(qb.x, i2*4+0) P2E(qb.y, i2*4+1) P2E(qb.z, i2*4+2) P2E(qb.w, i2*4+3)
    }
  }
#undef P2E
  #pragma unroll
  for (int d=32; d>0; d>>=1) kc += __shfl_down(kc, d, 64);
  if (ln==0) wru1[wv] = kc;
  __syncthreads();
  if (t==0){ u32 K2=0u; for (int w=0;w<NW;w++) K2 += wru1[w]; sh_u3 = K2; }
  __syncthreads();
  const u32 K = sh_u3;
  const bool kval = (K >= (u32)tk);
  const u32 llen = sh_len;

  cross4096_mass(massI, aux64, topp[b], &sh_tfix, &sh_idx, &sh_bef64, t);
  __syncthreads();
  const u32 b1p = sh_idx;
  const u64 t1  = sh_tfix - sh_bef64;
  const bool needK = kval && (b1p <= b1k);
  const bool needP = (!kval) || (b1p >= b1k);

  u32 kkey = 0u, pkey = 0u;

  if (fastOK){
    if (needK){
      for (int i=t;i<NB;i+=BLK) cnt[i]=0u;
      __syncthreads();
      for (u32 i=t; i<llen; i+=BLK){
        u32 key = (u32)(list[i]>>32);
        if ((key>>20) == b1k) atomicAdd(&cnt[(key>>8)&0xFFFu], 1u);
      }
      __syncthreads();
      cross4096_u32(cnt, aux32, r1-1u, &sh_idx, &sh_bef32, t);
      __syncthreads();
      u32 b2k = sh_idx, r2 = r1 - sh_bef32;
      u32 prefk = (b1k<<12) | b2k;
      for (int i=t;i<256;i+=BLK) cnt[i]=0u;
      __syncthreads();
      for (u32 i=t; i<llen; i+=BLK){
        u32 key = (u32)(list[i]>>32);
        if ((key>>8) == prefk) atomicAdd(&cnt[key&0xFFu], 1u);
      }
      __syncthreads();
      cross256_u32(cnt, r2-1u, &sh_idx, t);
      __syncthreads();
      kkey = (prefk<<8) | sh_idx;
    }
    if (needP){
      for (int i=t;i<NB;i+=BLK) massI[i]=0ull;
      __syncthreads();
      for (u32 i=t; i<llen; i+=BLK){
        u32 key = (u32)(list[i]>>32);
        if ((key>>20) == b1p && key >= lstar){
          u64 lm = (u64)__expf(fmaf(key2f(key), invT, cs));
          if (lm) atomicAdd(&massI[(key>>8)&0xFFFu], lm);
        }
      }
      __syncthreads();
      cross4096_u64(massI, aux64, t1, &sh_idx, &sh_bef64, t);
      __syncthreads();
      u32 b2p = sh_idx; u64 t2 = t1 - sh_bef64;
      u32 prefp = (b1p<<12) | b2p;
      for (int i=t;i<256;i+=BLK) massI[i]=0ull;
      __syncthreads();
      for (u32 i=t; i<llen; i+=BLK){
        u32 key = (u32)(list[i]>>32);
        if ((key>>8) == prefp && key >= lstar){
          u64 lm = (u64)__expf(fmaf(key2f(key), invT, cs));
          if (lm) atomicAdd(&massI[key&0xFFu], lm);
        }
      }
      __syncthreads();
      cross256_u64(massI, t2, &sh_idx, t);
      __syncthreads();
      pkey = (prefp<<8) | sh_idx;
    }
    const u32 thrkey = kkey > pkey ? kkey : pkey;

    float best = -INFINITY; u32 bi = 0xFFFFFFFFu;
    for (u32 i=t; i<llen; i+=BLK){
      u64 e = list[i];
      u32 key = (u32)(e>>32);
      if (key >= thrkey){
        u32 idx = (u32)e;
        u32 c = (u32)b * (u32)VOCAB + idx;
        float cand = key2f(key)*invT + bits2gumbel(gumbel_bits(c));
        if (cand > best || (cand == best && idx < bi)){ best = cand; bi = idx; }
      }
    }
    argmax_write(best, bi, wrf1, wru1, ln, wv, b, out);
    return;
  }

  for (int i=t;i<NB;i+=BLK){ cnt[i]=0u; massI[i]=0ull; }
  __syncthreads();
  for (int i=t; i<NV4; i+=BLK){
    float4 q = row4[i];
    #pragma unroll
    for (int j=0;j<4;j++){
      float l = (&q.x)[j]; u32 key = f2key(l); u32 hb = key>>20;
      if (needK && hb == b1k) atomicAdd(&cnt[(key>>8)&0xFFFu], 1u);
      if (needP && hb == b1p && key >= lstar){
        u64 lm = (u64)__expf(fmaf(l, invT, cs));
        if (lm) atomicAdd(&massI[(key>>8)&0xFFFu], lm);
      }
    }
  }
  __syncthreads();
  u32 b2k = 0u, r2 = 1u, b2p = 0u; u64 t2 = 0ull;
  if (needK){
    cross4096_u32(cnt, aux32, r1-1u, &sh_idx, &sh_bef32, t);
    __syncthreads();
    b2k = sh_idx; r2 = r1 - sh_bef32;
  }
  if (needP){
    cross4096_u64(massI, aux64, t1, &sh_idx, &sh_bef64, t);
    __syncthreads();
    b2p = sh_idx; t2 = t1 - sh_bef64;
  }
  const u32 prefk = (b1k<<12) | b2k;
  const u32 prefp = (b1p<<12) | b2p;
  for (int i=t;i<256;i+=BLK){ cnt[i]=0u; massI[i]=0ull; }
  __syncthreads();
  for (int i=t; i<NV4; i+=BLK){
    float4 q = row4[i];
    #pragma unroll
    for (int j=0;j<4;j++){
      float l = (&q.x)[j]; u32 key = f2key(l);
      if (needK && (key>>8) == prefk) atomicAdd(&cnt[key&0xFFu], 1u);
      if (needP && (key>>8) == prefp && key >= lstar){
        u64 lm = (u64)__expf(fmaf(l, invT, cs));
        if (lm) atomicAdd(&massI[key&0xFFu], lm);
      }
    }
  }
  __syncthreads();
  if (needK){
    cross256_u32(cnt, r2-1u, &sh_idx, t);
    __syncthreads();
    kkey = (prefk<<8) | sh_idx;
  }
  if (needP){
    cross256_u64(massI, t2, &sh_idx, t);
    __syncthreads();
    pkey = (prefp<<8) | sh_idx;
  }
  const float thrf = key2f(kkey > pkey ? kkey : pkey);
  float best = -INFINITY; u32 bi = 0xFFFFFFFFu;
  for (int i=t; i<NV4; i+=BLK){
    float4 q = row4[i];
    #pragma unroll
    for (int j=0;j<4;j++){
      float l = (&q.x)[j];
      if (l >= thrf){
        u32 idx = (u32)(i*4+j);
        u32 c = (u32)b * (u32)VOCAB + idx;
        float cand = l*invT + bits2gumbel(gumbel_bits(c));
        if (cand > best || (cand == best && idx < bi)){ best = cand; bi = idx; }
      }
    }
  }
  argmax_write(best, bi, wrf1, wru1, ln, wv, b, out);
}

extern "C" void kernel_launch(void* const* d_in, const int* in_sizes, int n_in,
                              void* d_out, int out_size, void* d_ws, size_t ws_size,
                              hipStream_t stream)
{
  const float* logits = (const float*)d_in[0];
  const float* temp   = (const float*)d_in[1];
  const float* minp   = (const float*)d_in[2];
  const int*   topk   = (const int*)d_in[3];
  const float* topp   = (const float*)d_in[4];
  int* out = (int*)d_out;
  char* ws = (char*)d_ws;

  int maxb = 0;
  hipError_t oe = hipOccupancyMaxActiveBlocksPerMultiprocessor(&maxb, k_coop, BLK, 0);
  const bool coop_ok = (ws_size >= (size_t)WS_NEED) && (oe == hipSuccess) && (maxb >= 2);

  if (coop_ok){
    void* args[] = { (void*)&logits, (void*)&temp, (void*)&minp, (void*)&topk,
                     (void*)&topp, (void*)&out, (void*)&ws };
    hipLaunchCooperativeKernel(k_coop, dim3(2*NROWS), dim3(BLK), args, 0, stream);
  } else {
    hipLaunchKernelGGL(k_single, dim3(NROWS), dim3(BLK), 0, stream,
                       logits, temp, minp, topk, topp, out);
  }
}

// Round 10
// 59.208 us; speedup vs baseline: 1.0332x; 1.0033x over previous
//
#include <hip/hip_runtime.h>
#include <stdint.h>

typedef unsigned long long u64;
typedef unsigned int u32;

#define VOCAB 128000
#define NV4   32000      // VOCAB/4
#define HV4   16000      // float4s per half-row
#define NROWS 256
#define BLK   1024
#define NW    16
#define NB    4096
#define CAPL  2048       // coop per-row list capacity (exact precheck + slow path)
#define CAPLS 4096       // fallback single-kernel list capacity
#define SEPS  1e-5f
#define LN2X40 27.725887222397812f   /* 40*ln2 */

// ---------- ws layout (bytes) ----------
#define WS_MASSH   0ull                      /* u64[512][4096] = 16 MB  */
#define WS_LIST    16777216ull               /* u64[256][2048] = 4 MB   */
#define WS_CNTH    20971520ull               /* u32[512][4096] = 8 MB   */
#define WS_PARTS   29360128ull               /* f32[512] Z' partials    */
#define WS_PARTK   29362176ull               /* u32[512] max-key        */
#define WS_PARTGV  29364224ull               /* f32[512] greedy max     */
#define WS_PARTGI  29366272ull               /* u32[512] greedy idx     */
#define WS_LL      29368320ull               /* u32[256] list len       */
#define WS_KP      29369344ull               /* u32[256] kept count     */
#define WS_FLAGA   29370368ull               /* u32[512] phase-A flags  */
#define WS_FLAGC   29372416ull               /* u32[512] phase-C flags  */
#define WS_NEED    29374464ull

// ---------- helpers ----------
__device__ __forceinline__ u32 f2key(float f){
  u32 u = __float_as_uint(f);
  return (u & 0x80000000u) ? ~u : (u | 0x80000000u);   // order-preserving
}
__device__ __forceinline__ float key2f(u32 k){
  u32 u = (k & 0x80000000u) ? (k ^ 0x80000000u) : ~k;
  return __uint_as_float(u);
}

// JAX threefry2x32, key (0,42)
__device__ __forceinline__ void tf2x32(u32 x0, u32 x1, u32 &o0, u32 &o1){
  const u32 k0 = 0u, k1 = 42u, k2 = 0u ^ 42u ^ 0x1BD11BDAu;
  x0 += k0; x1 += k1;
#define TFR(r) { x0 += x1; x1 = (x1 << (r)) | (x1 >> (32 - (r))); x1 ^= x0; }
  TFR(13) TFR(15) TFR(26) TFR(6)
  x0 += k1; x1 += k2 + 1u;
  TFR(17) TFR(29) TFR(16) TFR(24)
  x0 += k2; x1 += k0 + 2u;
  TFR(13) TFR(15) TFR(26) TFR(6)
  x0 += k0; x1 += k1 + 3u;
  TFR(17) TFR(29) TFR(16) TFR(24)
  x0 += k1; x1 += k2 + 4u;
  TFR(13) TFR(15) TFR(26) TFR(6)
  x0 += k2; x1 += k0 + 5u;
#undef TFR
  o0 = x0; o1 = x1;
}
__device__ __forceinline__ u32 gumbel_bits(u32 i){
  u32 o0, o1; tf2x32(0u, i, o0, o1);
  return o0 ^ o1;
}
__device__ __forceinline__ float bits2gumbel(u32 b){
  float f = __uint_as_float(0x3F800000u | (b >> 9)) - 1.0f;  // [0,1)
  float u = fmaxf(1e-10f, f + 1e-10f);
  return -logf(-logf(u));
}

// ---------- crossing searches (reduce + wave-0 descent) ----------
__device__ __forceinline__ void cross4096_u32(
    const u32* arr, u32* aux, u32 target, u32* out_idx, u32* out_before, int t)
{
  aux[t] = arr[4*t+0] + arr[4*t+1] + arr[4*t+2] + arr[4*t+3];
  __syncthreads();
  if (t < 64){
    u32 gs = 0u;
    #pragma unroll
    for (int j=0;j<16;j++) gs += aux[t*16+j];
    u32 pref = gs;
    #pragma unroll
    for (int d=1; d<64; d<<=1){ u32 v = __shfl_up(pref, d, 64); if (t >= d) pref += v; }
    u64 bal = __ballot(pref > target);
    int g = bal ? (__ffsll((long long)bal) - 1) : 63;
    u32 pg = __shfl(pref, g, 64);
    u32 gg = __shfl(gs, g, 64);
    if (t == 0){
      u32 c = pg - gg;
      u32 idx = (u32)(g*64 + 63);
      for (int j=0;j<16;j++){
        u32 v = aux[g*16+j];
        if (c + v > target){
          int base = (g*16+j)*4;
          for (int q=0;q<4;q++){
            u32 w = arr[base+q];
            if (c + w > target){ idx = (u32)(base+q); goto doneu; }
            c += w;
          }
        }
        c += v;
      }
      doneu:
      *out_idx = idx; *out_before = c;
    }
  }
}

__device__ __forceinline__ void cross4096_u64(
    const u64* arr, u64* aux, u64 target, u32* out_idx, u64* out_before, int t)
{
  aux[t] = arr[4*t+0] + arr[4*t+1] + arr[4*t+2] + arr[4*t+3];
  __syncthreads();
  if (t < 64){
    u64 gs = 0ull;
    #pragma unroll
    for (int j=0;j<16;j++) gs += aux[t*16+j];
    u64 pref = gs;
    #pragma unroll
    for (int d=1; d<64; d<<=1){
      u64 v = __shfl_up((unsigned long long)pref, d, 64); if (t >= d) pref += v;
    }
    u64 bal = __ballot(pref > target);
    int g = bal ? (__ffsll((long long)bal) - 1) : 63;
    u64 pg = __shfl((unsigned long long)pref, g, 64);
    u64 gg = __shfl((unsigned long long)gs, g, 64);
    if (t == 0){
      u64 c = pg - gg;
      u32 idx = (u32)(g*64 + 63);
      for (int j=0;j<16;j++){
        u64 v = aux[g*16+j];
        if (c + v > target){
          int base = (g*16+j)*4;
          for (int q=0;q<4;q++){
            u64 w = arr[base+q];
            if (c + w > target){ idx = (u32)(base+q); goto donev; }
            c += w;
          }
        }
        c += v;
      }
      donev:
      *out_idx = idx; *out_before = c;
    }
  }
}

// level-1 mass: derives total and target = (1-topp)*total internally
__device__ __forceinline__ void cross4096_mass(
    const u64* arr, u64* aux, float topp_v, u64* out_target,
    u32* out_idx, u64* out_before, int t)
{
  aux[t] = arr[4*t+0] + arr[4*t+1] + arr[4*t+2] + arr[4*t+3];
  __syncthreads();
  if (t < 64){
    u64 gs = 0ull;
    #pragma unroll
    for (int j=0;j<16;j++) gs += aux[t*16+j];
    u64 pref = gs;
    #pragma unroll
    for (int d=1; d<64; d<<=1){
      u64 v = __shfl_up((unsigned long long)pref, d, 64); if (t >= d) pref += v;
    }
    u64 total = __shfl((unsigned long long)pref, 63, 64);
    u64 target = (u64)((double)(1.0f - topp_v) * (double)total);
    u64 bal = __ballot(pref > target);
    int g = bal ? (__ffsll((long long)bal) - 1) : 63;
    u64 pg = __shfl((unsigned long long)pref, g, 64);
    u64 gg = __shfl((unsigned long long)gs, g, 64);
    if (t == 0){
      u64 c = pg - gg;
      u32 idx = (u32)(g*64 + 63);
      for (int j=0;j<16;j++){
        u64 v = aux[g*16+j];
        if (c + v > target){
          int base = (g*16+j)*4;
          for (int q=0;q<4;q++){
            u64 w = arr[base+q];
            if (c + w > target){ idx = (u32)(base+q); goto donem; }
            c += w;
          }
        }
        c += v;
      }
      donem:
      *out_target = target; *out_idx = idx; *out_before = c;
    }
  }
}

__device__ __forceinline__ void cross256_u32(const u32* arr, u32 target, u32* out_idx, int t){
  if (t < 64){
    u32 gs = arr[4*t+0]+arr[4*t+1]+arr[4*t+2]+arr[4*t+3];
    u32 pref = gs;
    #pragma unroll
    for (int d=1; d<64; d<<=1){ u32 v=__shfl_up(pref,d,64); if (t>=d) pref+=v; }
    u64 bal = __ballot(pref > target);
    int g = bal ? (__ffsll((long long)bal)-1) : 63;
    u32 pg=__shfl(pref,g,64), gg=__shfl(gs,g,64);
    if (t==0){
      u32 c = pg-gg; u32 idx=(u32)(g*4+3);
      for (int q=0;q<4;q++){ u32 w=arr[g*4+q]; if (c+w>target){ idx=(u32)(g*4+q); break; } c+=w; }
      *out_idx = idx;
    }
  }
}
__device__ __forceinline__ void cross256_u64(const u64* arr, u64 target, u32* out_idx, int t){
  if (t < 64){
    u64 gs = arr[4*t+0]+arr[4*t+1]+arr[4*t+2]+arr[4*t+3];
    u64 pref = gs;
    #pragma unroll
    for (int d=1; d<64; d<<=1){
      u64 v=__shfl_up((unsigned long long)pref,d,64); if (t>=d) pref+=v;
    }
    u64 bal = __ballot(pref > target);
    int g = bal ? (__ffsll((long long)bal)-1) : 63;
    u64 pg=__shfl((unsigned long long)pref,g,64), gg=__shfl((unsigned long long)gs,g,64);
    if (t==0){
      u64 c = pg-gg; u32 idx=(u32)(g*4+3);
      for (int q=0;q<4;q++){ u64 w=arr[g*4+q]; if (c+w>target){ idx=(u32)(g*4+q); break; } c+=w; }
      *out_idx = idx;
    }
  }
}

__device__ __forceinline__ void msmerge(float &m1, float &S1, float m2, float S2){
  float mm = fmaxf(m1, m2);
  if (mm == -INFINITY){ m1 = mm; S1 = 0.0f; return; }
  S1 = S1*__expf(m1-mm) + S2*__expf(m2-mm);
  m1 = mm;
}

// block argmax (larger value, then smaller idx) -> out[b]
__device__ __forceinline__ void argmax_write(
    float best, u32 bi, float* wrf, u32* wru, int ln, int wv, int b, int* out)
{
  #pragma unroll
  for (int d=32; d>0; d>>=1){
    float c2=__shfl_down(best,d,64); u32 i2=__shfl_down(bi,d,64);
    if (c2>best || (c2==best && i2<bi)){best=c2;bi=i2;}
  }
  if (ln==0){ wrf[wv]=best; wru[wv]=bi; }
  __syncthreads();
  if (wv==0){
    float b1=(ln<NW)?wrf[ln]:-INFINITY; u32 i1=(ln<NW)?wru[ln]:0xFFFFFFFFu;
    #pragma unroll
    for (int d=32; d>0; d>>=1){
      float b2=__shfl_down(b1,d,64); u32 i2=__shfl_down(i1,d,64);
      if (b2>b1 || (b2==b1 && i2<i1)){b1=b2;i1=i2;}
    }
    if (ln==0) out[b]=(int)i1;
  }
}

// =================== cooperative kernel: 2 blocks per row, flag-paired ===================
__global__ __launch_bounds__(BLK, 8) void k_coop(
    const float* __restrict__ logits, const float* __restrict__ temp,
    const float* __restrict__ minp, const int* __restrict__ topk,
    const float* __restrict__ topp, int* __restrict__ out, char* __restrict__ ws)
{
  __shared__ u32 cnt[NB];          // 16KB
  __shared__ u64 massI[NB];        // 32KB
  __shared__ u64 list[CAPL];       // 16KB
  __shared__ u64 aux64[BLK];       // 8KB
  __shared__ float wrf1[NW];
  __shared__ u32  wru1[NW], wru2[NW];
  __shared__ u32 sh_idx, sh_bef32, sh_lstar, sh_u1, sh_u2;
  __shared__ u64 sh_bef64, sh_tfix;

  u32* aux32 = (u32*)aux64;
  u64* massH  = (u64*)(ws + WS_MASSH);
  u64* wsList = (u64*)(ws + WS_LIST);
  u32* cntH   = (u32*)(ws + WS_CNTH);
  float* partS  = (float*)(ws + WS_PARTS);
  u32*   partK  = (u32*)(ws + WS_PARTK);
  float* partGV = (float*)(ws + WS_PARTGV);
  u32*   partGI = (u32*)(ws + WS_PARTGI);
  u32*   LL     = (u32*)(ws + WS_LL);
  u32*   KP     = (u32*)(ws + WS_KP);
  u32*   flagA  = (u32*)(ws + WS_FLAGA);
  u32*   flagC  = (u32*)(ws + WS_FLAGC);

  const int bid = blockIdx.x;
  const int r = bid >> 1;
  const int h = bid & 1;
  const int t = threadIdx.x;
  const int ln = t & 63, wv = t >> 6;
  const float T = temp[r];
  const bool greedy = (T < SEPS);
  const float invT = greedy ? 1.0f : (1.0f / T);
  const float* row = logits + (size_t)r * VOCAB;
  const float4* row4 = (const float4*)row;
  const int hb4 = h * HV4, he4 = hb4 + HV4;

  // per-launch zero of the pair accumulators (ordered before my flagA release)
  if (t == 0 && h == 0){ atomicExch(&LL[r], 0u); atomicExch(&KP[r], 0u); }

  // ======================= greedy rows: pairwise argmax, no convoy =======================
  if (greedy){
    float M = -INFINITY; u32 Mi = 0xFFFFFFFFu;
    for (int i = hb4 + t; i < he4; i += BLK){
      float4 q = row4[i];
      #pragma unroll
      for (int j=0;j<4;j++){
        float l = (&q.x)[j]; u32 gi = (u32)(i*4+j);
        if (l > M){ M = l; Mi = gi; }
      }
    }
    #pragma unroll
    for (int d=32; d>0; d>>=1){
      float M2=__shfl_down(M,d,64); u32 I2=__shfl_down(Mi,d,64);
      if (M2>M || (M2==M && I2<Mi)){ M=M2; Mi=I2; }
    }
    if (ln==0){ wrf1[wv]=M; wru1[wv]=Mi; }
    __syncthreads();
    if (t==0){
      float b1=wrf1[0]; u32 i1=wru1[0];
      for (int w=1; w<NW; w++){
        if (wrf1[w]>b1 || (wrf1[w]==b1 && wru1[w]<i1)){ b1=wrf1[w]; i1=wru1[w]; }
      }
      partGV[bid]=b1; partGI[bid]=i1;
      __threadfence();
      atomicExch(&flagA[bid], 1u);
      if (h==0){
        while (atomicAdd(&flagA[bid^1], 0u) == 0u) __builtin_amdgcn_s_sleep(2);
        __threadfence();
        float vA=partGV[bid], vB=partGV[bid^1];
        u32 iA=partGI[bid], iB=partGI[bid^1];
        out[r] = (vB>vA || (vB==vA && iB<iA)) ? (int)iB : (int)iA;
      }
    }
    return;
  }

  // ======================= PHASE A: half-row hist + Z partial =======================
  for (int i=t;i<NB;i+=BLK) cnt[i]=0u;
  __syncthreads();
  {
    u32 km = 0u;
    float S0=0.0f,S1=0.0f,S2=0.0f,S3=0.0f;
#define PA(LV, SS) { \
    float l_=(LV); u32 k_=f2key(l_); \
    if (k_>km) km=k_; \
    atomicAdd(&cnt[k_>>20], 1u); \
    SS += __expf(l_*invT); }
    for (int i = hb4 + t; i < he4; i += 2*BLK){
      float4 qa = row4[i];
      int i2 = i + BLK; bool h2 = (i2 < he4);
      float4 qb; if (h2) qb = row4[i2];
      PA(qa.x,S0) PA(qa.y,S1) PA(qa.z,S2) PA(qa.w,S3)
      if (h2){ PA(qb.x,S0) PA(qb.y,S1) PA(qb.z,S2) PA(qb.w,S3) }
    }
#undef PA
    float S = (S0+S1)+(S2+S3);
    #pragma unroll
    for (int d=32; d>0; d>>=1){
      S += __shfl_down(S,d,64);
      u32 k2 = __shfl_down(km,d,64); if (k2>km) km=k2;
    }
    if (ln==0){ wrf1[wv]=S; wru1[wv]=km; }
    __syncthreads();                    // cnt atomics + partials done
    for (int i=t;i<NB;i+=BLK) cntH[(size_t)bid*NB + i] = cnt[i];
    if (t==0){
      float St=0.0f; u32 kt=0u;
      for (int w=0; w<NW; w++){ St += wrf1[w]; if (wru1[w]>kt) kt=wru1[w]; }
      partS[bid]=St; partK[bid]=kt;
    }
  }
  // ---- pairwise handshake A (release own, acquire partner) ----
  __syncthreads();
  if (t==0){
    __threadfence();
    atomicExch(&flagA[bid], 1u);
    while (atomicAdd(&flagA[bid^1], 0u) == 0u) __builtin_amdgcn_s_sleep(2);
    __threadfence();
  }
  __syncthreads();

  // ======================= PHASE B (both blocks, redundant) =======================
  float m=0.0f, Z=1.0f, cs=0.0f;
  u32 b1k=0u, r1=1u, lstar=0u, CLB=0u;
  int tk=1; bool kcert=false, fastOK=false;

  {
    const int pb = bid ^ 1;
    for (int i=t;i<NB;i+=BLK) cnt[i] += cntH[(size_t)pb*NB + i];
    {
      u32 kA = partK[bid & ~1], kB = partK[bid | 1];
      float SA = partS[bid & ~1], SB = partS[bid | 1];
      u32 kmax = kA > kB ? kA : kB;
      m = key2f(kmax) * invT;
      Z = (SA + SB) * __expf(-m);
    }
    cs = LN2X40 - m;
    __syncthreads();

    tk = topk[r]; if (tk < 1) tk = 1; if (tk > VOCAB) tk = VOCAB;
    cross4096_u32(cnt, aux32, (u32)(VOCAB - tk), &sh_idx, &sh_bef32, t);
    __syncthreads();
    b1k = sh_idx;
    r1  = (u32)(VOCAB - tk + 1) - sh_bef32;

    // min-p raw cutoff l*: wave-parallel monotone search
    if (wv==0){
      const float rhs = minp[r] * (1.0f / Z);
      u32 lo = 0u, hi = 0xFF800000u;
      while (hi - lo > 64u){
        u32 step = (hi - lo) >> 6;
        u32 k = lo + (u32)(ln + 1) * step;
        float e = __expf(fmaf(key2f(k), invT, -m));
        u64 bal = __ballot((e / Z) >= rhs);
        if (bal){
          u32 g = (u32)(__ffsll((long long)bal) - 1);
          hi = lo + (g + 1u) * step;
          lo = lo + g * step;
        } else {
          lo += 64u * step;
        }
      }
      u32 k = lo + 1u + (u32)ln;
      bool ok = (k <= hi);
      float e = __expf(fmaf(key2f(k), invT, -m));
      u64 bal = __ballot(ok && ((e / Z) >= rhs));
      if (ln==0) sh_lstar = bal ? (lo + 1u + (u32)(__ffsll((long long)bal) - 1)) : hi;
    }
    __syncthreads();
    lstar = sh_lstar;
    const u32 bl = lstar >> 20;

    // Kmin (#tokens buckets > bl), pc (#tokens buckets >= b1k)
    {
      u32 pa=0u, pc=0u;
      for (int i=t;i<NB;i+=BLK){
        u32 c = cnt[i];
        if ((u32)i > bl)   pa += c;
        if ((u32)i >= b1k) pc += c;
      }
      #pragma unroll
      for (int d=32; d>0; d>>=1){ pa += __shfl_down(pa,d,64); pc += __shfl_down(pc,d,64); }
      if (ln==0){ wru1[wv]=pa; wru2[wv]=pc; }
      __syncthreads();
      if (t==0){
        u32 a=0u, c2=0u;
        for (int w=0; w<NW; w++){ a += wru1[w]; c2 += wru2[w]; }
        sh_u1 = a; sh_u2 = c2;
      }
      __syncthreads();
    }
    const u32 Kmin = sh_u1;
    kcert = (Kmin >= (u32)tk);
    CLB = kcert ? b1k : bl;
    const u32 listCnt = kcert ? sh_u2 : (Kmin + cnt[bl]);
    fastOK = (listCnt <= (u32)CAPL);
  }

  // ======================= PHASE C =======================
  {
    for (int i=t;i<NB;i+=BLK) massI[i]=0ull;
    __syncthreads();
    u32 kc = 0u;
#define PC(LV, IDX) { \
    float l_ = (LV); u32 key_ = f2key(l_); \
    if (key_ >= lstar){ \
      kc++; \
      u64 lm_ = (u64)__expf(fmaf(l_, invT, cs)); \
      if (lm_) atomicAdd(&massI[key_>>20], lm_); \
    } \
    bool cand_ = fastOK && ((key_>>20) >= CLB); \
    u64 bal_ = __ballot(cand_); \
    if (cand_){ \
      u32 lead_ = (u32)__ffsll((long long)bal_) - 1u; \
      u32 base_ = 0u; \
      if ((u32)ln == lead_) base_ = atomicAdd(&LL[r], (u32)__popcll(bal_)); \
      base_ = __shfl(base_, (int)lead_, 64); \
      u32 p_ = base_ + (u32)__popcll(bal_ & ((1ull << ln) - 1ull)); \
      if (p_ < CAPL) wsList[(size_t)r*CAPL + p_] = ((u64)key_ << 32) | (u64)(u32)(IDX); \
    } }
    for (int i = hb4 + t; i < he4; i += 2*BLK){
      float4 qa = row4[i];
      int i2 = i + BLK; bool h2 = (i2 < he4);
      float4 qb; if (h2) qb = row4[i2];
      PC(qa.x,i*4+0) PC(qa.y,i*4+1) PC(qa.z,i*4+2) PC(qa.w,i*4+3)
      if (h2){ PC(qb.x,i2*4+0) PC(qb.y,i2*4+1) PC(qb.z,i2*4+2) PC(qb.w,i2*4+3) }
    }
#undef PC
    #pragma unroll
    for (int d=32; d>0; d>>=1) kc += __shfl_down(kc, d, 64);
    if (ln==0) wru1[wv] = kc;
    __syncthreads();                   // mass atomics done
    if (t==0){
      u32 K2=0u; for (int w=0;w<NW;w++) K2 += wru1[w];
      atomicAdd(&KP[r], K2);
    }
  }
  if (h==1){
    for (int i=t;i<NB;i+=BLK) massH[(size_t)bid*NB + i] = massI[i];
    __syncthreads();
    if (t==0){ __threadfence(); atomicExch(&flagC[bid], 1u); }
    return;
  }
  // h==0: acquire partner C
  __syncthreads();
  if (t==0){
    while (atomicAdd(&flagC[bid^1], 0u) == 0u) __builtin_amdgcn_s_sleep(2);
    __threadfence();
    sh_u1 = atomicAdd(&KP[r], 0u);
    sh_u2 = atomicAdd(&LL[r], 0u);
  }
  __syncthreads();

  // ======================= PHASE D (h==0 only) =======================
  for (int i=t;i<NB;i+=BLK) massI[i] += massH[(size_t)(bid+1)*NB + i];
  const u32 K = sh_u1;
  const bool kval = (K >= (u32)tk);
  u32 llen = sh_u2; if (llen > (u32)CAPL) llen = CAPL;
  __syncthreads();

  cross4096_mass(massI, aux64, topp[r], &sh_tfix, &sh_idx, &sh_bef64, t);
  __syncthreads();
  const u32 b1p = sh_idx;
  const u64 t1  = sh_tfix - sh_bef64;
  const bool needK = kval && (b1p <= b1k);
  const bool needP = (!kval) || (b1p >= b1k);

  u32 kkey = 0u, pkey = 0u;

  if (fastOK){
    for (u32 i=t; i<llen; i+=BLK) list[i] = wsList[(size_t)r*CAPL + i];
    __syncthreads();
    if (needK){
      for (int i=t;i<NB;i+=BLK) cnt[i]=0u;
      __syncthreads();
      for (u32 i=t; i<llen; i+=BLK){
        u32 key = (u32)(list[i]>>32);
        if ((key>>20) == b1k) atomicAdd(&cnt[(key>>8)&0xFFFu], 1u);
      }
      __syncthreads();
      cross4096_u32(cnt, aux32, r1-1u, &sh_idx, &sh_bef32, t);
      __syncthreads();
      u32 b2k = sh_idx, r2 = r1 - sh_bef32;
      u32 prefk = (b1k<<12) | b2k;
      for (int i=t;i<256;i+=BLK) cnt[i]=0u;
      __syncthreads();
      for (u32 i=t; i<llen; i+=BLK){
        u32 key = (u32)(list[i]>>32);
        if ((key>>8) == prefk) atomicAdd(&cnt[key&0xFFu], 1u);
      }
      __syncthreads();
      cross256_u32(cnt, r2-1u, &sh_idx, t);
      __syncthreads();
      kkey = (prefk<<8) | sh_idx;
    }
    if (needP){
      for (int i=t;i<NB;i+=BLK) massI[i]=0ull;
      __syncthreads();
      for (u32 i=t; i<llen; i+=BLK){
        u32 key = (u32)(list[i]>>32);
        if ((key>>20) == b1p && key >= lstar){
          u64 lm = (u64)__expf(fmaf(key2f(key), invT, cs));
          if (lm) atomicAdd(&massI[(key>>8)&0xFFFu], lm);
        }
      }
      __syncthreads();
      cross4096_u64(massI, aux64, t1, &sh_idx, &sh_bef64, t);
      __syncthreads();
      u32 b2p = sh_idx; u64 t2 = t1 - sh_bef64;
      u32 prefp = (b1p<<12) | b2p;
      for (int i=t;i<256;i+=BLK) massI[i]=0ull;
      __syncthreads();
      for (u32 i=t; i<llen; i+=BLK){
        u32 key = (u32)(list[i]>>32);
        if ((key>>8) == prefp && key >= lstar){
          u64 lm = (u64)__expf(fmaf(key2f(key), invT, cs));
          if (lm) atomicAdd(&massI[key&0xFFu], lm);
        }
      }
      __syncthreads();
      cross256_u64(massI, t2, &sh_idx, t);
      __syncthreads();
      pkey = (prefp<<8) | sh_idx;
    }
    const u32 thrkey = kkey > pkey ? kkey : pkey;

    float best = -INFINITY; u32 bi = 0xFFFFFFFFu;
    for (u32 i=t; i<llen; i+=BLK){
      u64 e = list[i];
      u32 key = (u32)(e>>32);
      if (key >= thrkey){
        u32 idx = (u32)e;
        u32 c = (u32)r * (u32)VOCAB + idx;
        float cand = key2f(key)*invT + bits2gumbel(gumbel_bits(c));
        if (cand > best || (cand == best && idx < bi)){ best = cand; bi = idx; }
      }
    }
    argmax_write(best, bi, wrf1, wru1, ln, wv, r, out);
    return;
  }

  // ---- slow path: full-row restream refinement + sampling ----
  for (int i=t;i<NB;i+=BLK) cnt[i]=0u;
  __syncthreads();
  for (int i=t;i<NB;i+=BLK) massI[i]=0ull;
  __syncthreads();
  for (int i=t; i<NV4; i+=BLK){
    float4 q = row4[i];
    #pragma unroll
    for (int j=0;j<4;j++){
      float l = (&q.x)[j]; u32 key = f2key(l); u32 hb = key>>20;
      if (needK && hb == b1k) atomicAdd(&cnt[(key>>8)&0xFFFu], 1u);
      if (needP && hb == b1p && key >= lstar){
        u64 lm = (u64)__expf(fmaf(l, invT, cs));
        if (lm) atomicAdd(&massI[(key>>8)&0xFFFu], lm);
      }
    }
  }
  __syncthreads();
  u32 b2k = 0u, r2 = 1u, b2p = 0u; u64 t2 = 0ull;
  if (needK){
    cross4096_u32(cnt, aux32, r1-1u, &sh_idx, &sh_bef32, t);
    __syncthreads();
    b2k = sh_idx; r2 = r1 - sh_bef32;
  }
  if (needP){
    cross4096_u64(massI, aux64, t1, &sh_idx, &sh_bef64, t);
    __syncthreads();
    b2p = sh_idx; t2 = t1 - sh_bef64;
  }
  const u32 prefk = (b1k<<12) | b2k;
  const u32 prefp = (b1p<<12) | b2p;
  for (int i=t;i<256;i+=BLK){ cnt[i]=0u; massI[i]=0ull; }
  __syncthreads();
  for (int i=t; i<NV4; i+=BLK){
    float4 q = row4[i];
    #pragma unroll
    for (int j=0;j<4;j++){
      float l = (&q.x)[j]; u32 key = f2key(l);
      if (needK && (key>>8) == prefk) atomicAdd(&cnt[key&0xFFu], 1u);
      if (needP && (key>>8) == prefp && key >= lstar){
        u64 lm = (u64)__expf(fmaf(l, invT, cs));
        if (lm) atomicAdd(&massI[key&0xFFu], lm);
      }
    }
  }
  __syncthreads();
  if (needK){
    cross256_u32(cnt, r2-1u, &sh_idx, t);
    __syncthreads();
    kkey = (prefk<<8) | sh_idx;
  }
  if (needP){
    cross256_u64(massI, t2, &sh_idx, t);
    __syncthreads();
    pkey = (prefp<<8) | sh_idx;
  }
  const float thrf = key2f(kkey > pkey ? kkey : pkey);
  float best = -INFINITY; u32 bi = 0xFFFFFFFFu;
  for (int i=t; i<NV4; i+=BLK){
    float4 q = row4[i];
    #pragma unroll
    for (int j=0;j<4;j++){
      float l = (&q.x)[j];
      if (l >= thrf){
        u32 idx = (u32)(i*4+j);
        u32 c = (u32)r * (u32)VOCAB + idx;
        float cand = l*invT + bits2gumbel(gumbel_bits(c));
        if (cand > best || (cand == best && idx < bi)){ best = cand; bi = idx; }
      }
    }
  }
  argmax_write(best, bi, wrf1, wru1, ln, wv, r, out);
}

// =================== fallback: r7 single-block kernel (proven 60 µs) ===================
__global__ __launch_bounds__(BLK) void k_single(
    const float* __restrict__ logits, const float* __restrict__ temp,
    const float* __restrict__ minp, const int* __restrict__ topk,
    const float* __restrict__ topp, int* __restrict__ out)
{
  __shared__ u32 cnt[NB];
  __shared__ u64 massI[NB];
  __shared__ u64 list[CAPLS];
  __shared__ u64 aux64[BLK];
  __shared__ float wrf1[NW], wrf2[NW];
  __shared__ u32  wru1[NW], wru2[NW];
  __shared__ float sh_m, sh_Z;
  __shared__ u32 sh_lstar, sh_len, sh_idx, sh_bef32, sh_u1, sh_u2, sh_u3;
  __shared__ u64 sh_bef64, sh_tfix;

  u32* aux32 = (u32*)aux64;

  const int b = blockIdx.x;
  const int t = threadIdx.x;
  const int ln = t & 63, wv = t >> 6;
  const float T = temp[b];
  const float* row = logits + (size_t)b * VOCAB;
  const float4* row4 = (const float4*)row;

  if (T < SEPS){
    float M = -INFINITY; u32 Mi = 0xFFFFFFFFu;
    for (int i=t; i<NV4; i+=BLK){
      float4 q = row4[i];
      #pragma unroll
      for (int j=0;j<4;j++){
        float l = (&q.x)[j]; u32 gi = (u32)(i*4+j);
        if (l > M){ M = l; Mi = gi; }
      }
    }
    argmax_write(M, Mi, wrf1, wru1, ln, wv, b, out);
    return;
  }

  const float invT = 1.0f / T;
  for (int i=t;i<NB;i+=BLK){ cnt[i]=0u; massI[i]=0ull; }
  if (t==0) sh_len=0u;
  __syncthreads();

  float ms0=-INFINITY,S0=0.0f, ms1=-INFINITY,S1=0.0f,
        ms2=-INFINITY,S2=0.0f, ms3=-INFINITY,S3=0.0f;
#define ONLINE(LV, MS, SS) { \
    float l_ = (LV); \
    atomicAdd(&cnt[f2key(l_)>>20], 1u); \
    float s_ = l_ * invT; \
    float d_ = s_ - MS; \
    float e_ = __expf(-fabsf(d_)); \
    if (d_ > 0.0f){ SS = fmaf(SS, e_, 1.0f); MS = s_; } else { SS += e_; } \
  }
  for (int i=t; i<NV4; i+=2*BLK){
    float4 qa = row4[i];
    int i2 = i + BLK; bool h2 = (i2 < NV4);
    float4 qb; if (h2) qb = row4[i2];
    ONLINE(qa.x,ms0,S0) ONLINE(qa.y,ms1,S1) ONLINE(qa.z,ms2,S2) ONLINE(qa.w,ms3,S3)
    if (h2){
      ONLINE(qb.x,ms0,S0) ONLINE(qb.y,ms1,S1) ONLINE(qb.z,ms2,S2) ONLINE(qb.w,ms3,S3)
    }
  }
#undef ONLINE
  msmerge(ms0,S0,ms1,S1); msmerge(ms2,S2,ms3,S3); msmerge(ms0,S0,ms2,S2);
  #pragma unroll
  for (int d=32; d>0; d>>=1){
    float mz = __shfl_down(ms0, d, 64); float Sz = __shfl_down(S0, d, 64);
    msmerge(ms0, S0, mz, Sz);
  }
  if (ln==0){ wrf1[wv]=ms0; wrf2[wv]=S0; }
  __syncthreads();
  if (wv==0){
    float m1 = (ln<NW)? wrf1[ln] : -INFINITY;
    float Sx = (ln<NW)? wrf2[ln] : 0.0f;
    #pragma unroll
    for (int d=32; d>0; d>>=1){
      float mz=__shfl_down(m1,d,64); float Sz=__shfl_down(Sx,d,64);
      msmerge(m1, Sx, mz, Sz);
    }
    if (ln==0){ sh_m = m1; sh_Z = Sx; }
  }
  __syncthreads();
  const float m = sh_m, Z = sh_Z;

  int tk = topk[b]; if (tk < 1) tk = 1; if (tk > VOCAB) tk = VOCAB;
  cross4096_u32(cnt, aux32, (u32)(VOCAB - tk), &sh_idx, &sh_bef32, t);
  __syncthreads();
  const u32 b1k = sh_idx;
  const u32 r1  = (u32)(VOCAB - tk + 1) - sh_bef32;

  if (wv==0){
    const float rhs = minp[b] * (1.0f / Z);
    u32 lo = 0u, hi = 0xFF800000u;
    while (hi - lo > 64u){
      u32 step = (hi - lo) >> 6;
      u32 k = lo + (u32)(ln + 1) * step;
      float e = __expf(fmaf(key2f(k), invT, -m));
      u64 bal = __ballot((e / Z) >= rhs);
      if (bal){
        u32 g = (u32)(__ffsll((long long)bal) - 1);
        hi = lo + (g + 1u) * step;
        lo = lo + g * step;
      } else {
        lo += 64u * step;
      }
    }
    u32 k = lo + 1u + (u32)ln;
    bool ok = (k <= hi);
    float e = __expf(fmaf(key2f(k), invT, -m));
    u64 bal = __ballot(ok && ((e / Z) >= rhs));
    if (ln==0) sh_lstar = bal ? (lo + 1u + (u32)(__ffsll((long long)bal) - 1)) : hi;
  }
  __syncthreads();
  const u32 lstar = sh_lstar;
  const u32 bl = lstar >> 20;

  {
    u32 pa=0u, pc=0u;
    for (int i=t;i<NB;i+=BLK){
      u32 c = cnt[i];
      if ((u32)i > bl)   pa += c;
      if ((u32)i >= b1k) pc += c;
    }
    #pragma unroll
    for (int d=32; d>0; d>>=1){ pa += __shfl_down(pa,d,64); pc += __shfl_down(pc,d,64); }
    if (ln==0){ wru1[wv]=pa; wru2[wv]=pc; }
    __syncthreads();
    if (t==0){
      u32 a=0u, c2=0u;
      for (int w=0; w<NW; w++){ a += wru1[w]; c2 += wru2[w]; }
      sh_u1 = a; sh_u2 = c2;
    }
    __syncthreads();
  }
  const u32 Kmin = sh_u1;
  const bool kcert = (Kmin >= (u32)tk);
  const u32 CLB = kcert ? b1k : bl;
  const u32 listlen = kcert ? sh_u2 : (Kmin + cnt[bl]);
  const bool fastOK = (listlen <= (u32)CAPLS);
  const float cs = LN2X40 - m;

  u32 kc = 0u;
#define P2E(LV, IDX) { \
    float l_ = (LV); u32 key_ = f2key(l_); \
    if (key_ >= lstar){ \
      kc++; \
      u64 lm_ = (u64)__expf(fmaf(l_, invT, cs)); \
      if (lm_) atomicAdd(&massI[key_>>20], lm_); \
    } \
    if (fastOK && (key_>>20) >= CLB){ \
      u32 p_ = atomicAdd(&sh_len, 1u); \
      if (p_ < CAPLS) list[p_] = ((u64)key_ << 32) | (u64)(u32)(IDX); \
    } \
  }
  for (int i=t; i<NV4; i+=2*BLK){
    float4 qa = row4[i];
    int i2 = i + BLK; bool h2 = (i2 < NV4);
    float4 qb; if (h2) qb = row4[i2];
    P2E(qa.x, i*4+0) P2E(qa.y, i*4+1) P2E(qa.z, i*4+2) P2E(qa.w, i*4+3)
    if (h2){
      P2E(qb.x, i2*4+0) P2E(qb.y, i2*4+1) P2E(qb.z, i2*4+2) P2E(qb.w, i2*4+3)
    }
  }
#undef P2E
  #pragma unroll
  for (int d=32; d>0; d>>=1) kc += __shfl_down(kc, d, 64);
  if (ln==0) wru1[wv] = kc;
  __syncthreads();
  if (t==0){ u32 K2=0u; for (int w=0;w<NW;w++) K2 += wru1[w]; sh_u3 = K2; }
  __syncthreads();
  const u32 K = sh_u3;
  const bool kval = (K >= (u32)tk);
  const u32 llen = sh_len;

  cross4096_mass(massI, aux64, topp[b], &sh_tfix, &sh_idx, &sh_bef64, t);
  __syncthreads();
  const u32 b1p = sh_idx;
  const u64 t1  = sh_tfix - sh_bef64;
  const bool needK = kval && (b1p <= b1k);
  const bool needP = (!kval) || (b1p >= b1k);

  u32 kkey = 0u, pkey = 0u;

  if (fastOK){
    if (needK){
      for (int i=t;i<NB;i+=BLK) cnt[i]=0u;
      __syncthreads();
      for (u32 i=t; i<llen; i+=BLK){
        u32 key = (u32)(list[i]>>32);
        if ((key>>20) == b1k) atomicAdd(&cnt[(key>>8)&0xFFFu], 1u);
      }
      __syncthreads();
      cross4096_u32(cnt, aux32, r1-1u, &sh_idx, &sh_bef32, t);
      __syncthreads();
      u32 b2k = sh_idx, r2 = r1 - sh_bef32;
      u32 prefk = (b1k<<12) | b2k;
      for (int i=t;i<256;i+=BLK) cnt[i]=0u;
      __syncthreads();
      for (u32 i=t; i<llen; i+=BLK){
        u32 key = (u32)(list[i]>>32);
        if ((key>>8) == prefk) atomicAdd(&cnt[key&0xFFu], 1u);
      }
      __syncthreads();
      cross256_u32(cnt, r2-1u, &sh_idx, t);
      __syncthreads();
      kkey = (prefk<<8) | sh_idx;
    }
    if (needP){
      for (int i=t;i<NB;i+=BLK) massI[i]=0ull;
      __syncthreads();
      for (u32 i=t; i<llen; i+=BLK){
        u32 key = (u32)(list[i]>>32);
        if ((key>>20) == b1p && key >= lstar){
          u64 lm = (u64)__expf(fmaf(key2f(key), invT, cs));
          if (lm) atomicAdd(&massI[(key>>8)&0xFFFu], lm);
        }
      }
      __syncthreads();
      cross4096_u64(massI, aux64, t1, &sh_idx, &sh_bef64, t);
      __syncthreads();
      u32 b2p = sh_idx; u64 t2 = t1 - sh_bef64;
      u32 prefp = (b1p<<12) | b2p;
      for (int i=t;i<256;i+=BLK) massI[i]=0ull;
      __syncthreads();
      for (u32 i=t; i<llen; i+=BLK){
        u32 key = (u32)(list[i]>>32);
        if ((key>>8) == prefp && key >= lstar){
          u64 lm = (u64)__expf(fmaf(key2f(key), invT, cs));
          if (lm) atomicAdd(&massI[key&0xFFu], lm);
        }
      }
      __syncthreads();
      cross256_u64(massI, t2, &sh_idx, t);
      __syncthreads();
      pkey = (prefp<<8) | sh_idx;
    }
    const u32 thrkey = kkey > pkey ? kkey : pkey;

    float best = -INFINITY; u32 bi = 0xFFFFFFFFu;
    for (u32 i=t; i<llen; i+=BLK){
      u64 e = list[i];
      u32 key = (u32)(e>>32);
      if (key >= thrkey){
        u32 idx = (u32)e;
        u32 c = (u32)b * (u32)VOCAB + idx;
        float cand = key2f(key)*invT + bits2gumbel(gumbel_bits(c));
        if (cand > best || (cand == best && idx < bi)){ best = cand; bi = idx; }
      }
    }
    argmax_write(best, bi, wrf1, wru1, ln, wv, b, out);
    return;
  }

  for (int i=t;i<NB;i+=BLK){ cnt[i]=0u; massI[i]=0ull; }
  __syncthreads();
  for (int i=t; i<NV4; i+=BLK){
    float4 q = row4[i];
    #pragma unroll
    for (int j=0;j<4;j++){
      float l = (&q.x)[j]; u32 key = f2key(l); u32 hb = key>>20;
      if (needK && hb == b1k) atomicAdd(&cnt[(key>>8)&0xFFFu], 1u);
      if (needP && hb == b1p && key >= lstar){
        u64 lm = (u64)__expf(fmaf(l, invT, cs));
        if (lm) atomicAdd(&massI[(key>>8)&0xFFFu], lm);
      }
    }
  }
  __syncthreads();
  u32 b2k = 0u, r2 = 1u, b2p = 0u; u64 t2 = 0ull;
  if (needK){
    cross4096_u32(cnt, aux32, r1-1u, &sh_idx, &sh_bef32, t);
    __syncthreads();
    b2k = sh_idx; r2 = r1 - sh_bef32;
  }
  if (needP){
    cross4096_u64(massI, aux64, t1, &sh_idx, &sh_bef64, t);
    __syncthreads();
    b2p = sh_idx; t2 = t1 - sh_bef64;
  }
  const u32 prefk = (b1k<<12) | b2k;
  const u32 prefp = (b1p<<12) | b2p;
  for (int i=t;i<256;i+=BLK){ cnt[i]=0u; massI[i]=0ull; }
  __syncthreads();
  for (int i=t; i<NV4; i+=BLK){
    float4 q = row4[i];
    #pragma unroll
    for (int j=0;j<4;j++){
      float l = (&q.x)[j]; u32 key = f2key(l);
      if (needK && (key>>8) == prefk) atomicAdd(&cnt[key&0xFFu], 1u);
      if (needP && (key>>8) == prefp && key >= lstar){
        u64 lm = (u64)__expf(fmaf(l, invT, cs));
        if (lm) atomicAdd(&massI[key&0xFFu], lm);
      }
    }
  }
  __syncthreads();
  if (needK){
    cross256_u32(cnt, r2-1u, &sh_idx, t);
    __syncthreads();
    kkey = (prefk<<8) | sh_idx;
  }
  if (needP){
    cross256_u64(massI, t2, &sh_idx, t);
    __syncthreads();
    pkey = (prefp<<8) | sh_idx;
  }
  const float thrf = key2f(kkey > pkey ? kkey : pkey);
  float best = -INFINITY; u32 bi = 0xFFFFFFFFu;
  for (int i=t; i<NV4; i+=BLK){
    float4 q = row4[i];
    #pragma unroll
    for (int j=0;j<4;j++){
      float l = (&q.x)[j];
      if (l >= thrf){
        u32 idx = (u32)(i*4+j);
        u32 c = (u32)b * (u32)VOCAB + idx;
        float cand = l*invT + bits2gumbel(gumbel_bits(c));
        if (cand > best || (cand == best && idx < bi)){ best = cand; bi = idx; }
      }
    }
  }
  argmax_write(best, bi, wrf1, wru1, ln, wv, b, out);
}

extern "C" void kernel_launch(void* const* d_in, const int* in_sizes, int n_in,
                              void* d_out, int out_size, void* d_ws, size_t ws_size,
                              hipStream_t stream)
{
  const float* logits = (const float*)d_in[0];
  const float* temp   = (const float*)d_in[1];
  const float* minp   = (const float*)d_in[2];
  const int*   topk   = (const int*)d_in[3];
  const float* topp   = (const float*)d_in[4];
  int* out = (int*)d_out;
  char* ws = (char*)d_ws;

  int maxb = 0;
  hipError_t oe = hipOccupancyMaxActiveBlocksPerMultiprocessor(&maxb, k_coop, BLK, 0);
  const bool coop_ok = (ws_size >= (size_t)WS_NEED) && (oe == hipSuccess) && (maxb >= 2);

  if (coop_ok){
    // zero the handshake flags each launch (graph-capture-legal async memset)
    hipMemsetAsync(ws + WS_FLAGA, 0, 4096, stream);
    void* args[] = { (void*)&logits, (void*)&temp, (void*)&minp, (void*)&topk,
                     (void*)&topp, (void*)&out, (void*)&ws };
    hipLaunchCooperativeKernel(k_coop, dim3(2*NROWS), dim3(BLK), args, 0, stream);
  } else {
    hipLaunchKernelGGL(k_single, dim3(NROWS), dim3(BLK), 0, stream,
                       logits, temp, minp, topk, topp, out);
  }
}